// Round 7
// baseline (302.702 us; speedup 1.0000x reference)
//
#include <hip/hip_runtime.h>
#include <math.h>

#define T_SEQ 4096
#define ROWS 8192
#define NCHUNK 128
#define CLEN 32

typedef __attribute__((ext_vector_type(4))) float f32x4;
typedef __attribute__((ext_vector_type(8))) short s16x8;

__device__ __forceinline__ float siluf(float x) { return x / (1.f + __expf(-x)); }
__device__ __forceinline__ float softplusf(float x) {
    return fmaxf(x, 0.f) + log1pf(__expf(-fabsf(x)));
}
__device__ __forceinline__ ushort f2b(float f) {
    uint u = __float_as_uint(f);
    u += 0x7fffu + ((u >> 16) & 1u);
    return (ushort)(u >> 16);
}
__device__ __forceinline__ float b2f(ushort h) { return __uint_as_float(((uint)h) << 16); }

// direct global->LDS, 16B per lane.  LDS dest is wave-uniform base + lane*16;
// global src is per-lane.
__device__ __forceinline__ void gl16(const ushort* g, const char* l)
{
    __builtin_amdgcn_global_load_lds(
        (const __attribute__((address_space(1))) void*)g,
        (__attribute__((address_space(3))) void*)l,
        16, 0, 0);
}

// ---------------------------------------------------------------------------
// fp32 -> bf16 bulk convert (8 elems/thread)
// ---------------------------------------------------------------------------
__global__ __launch_bounds__(256)
void cvt_bf16(const float* __restrict__ in, ushort* __restrict__ out)
{
    int i = blockIdx.x * 256 + threadIdx.x;
    const float4* p = reinterpret_cast<const float4*>(in) + (size_t)i * 2;
    float4 a = p[0], b = p[1];
    s16x8 v;
    v[0] = (short)f2b(a.x); v[1] = (short)f2b(a.y); v[2] = (short)f2b(a.z); v[3] = (short)f2b(a.w);
    v[4] = (short)f2b(b.x); v[5] = (short)f2b(b.y); v[6] = (short)f2b(b.z); v[7] = (short)f2b(b.w);
    *reinterpret_cast<s16x8*>(out + (size_t)i * 8) = v;
}

// ---------------------------------------------------------------------------
// W [Kdim][Ndim] fp32 -> WT [Ndim][Kdim] bf16
// ---------------------------------------------------------------------------
__global__ __launch_bounds__(256)
void transpose_w(const float* __restrict__ W, ushort* __restrict__ WT, int Kdim, int Ndim)
{
    int idx = blockIdx.x * 256 + threadIdx.x;
    int kg8 = Kdim >> 3;
    if (idx >= Ndim * kg8) return;
    int n = idx / kg8, kg = idx - n * kg8;
    s16x8 v;
    #pragma unroll
    for (int i = 0; i < 8; ++i)
        v[i] = (short)f2b(W[(size_t)(kg * 8 + i) * Ndim + n]);
    *reinterpret_cast<s16x8*>(WT + (size_t)n * Kdim + kg * 8) = v;
}

// ---------------------------------------------------------------------------
// Fused+transposed output weights: WT[j][d] = sum_m W_out[d][m]*merge[mrow0+m][j]
// ---------------------------------------------------------------------------
__global__ __launch_bounds__(256)
void fusewT(const float* __restrict__ W_out, const float* __restrict__ merge,
            ushort* __restrict__ WT, int mrow0)
{
    int idx = blockIdx.x * 256 + threadIdx.x;   // d*256 + j
    int dd = idx >> 8, j = idx & 255;
    float acc = 0.f;
    const float* wr = W_out + dd * 256;
    const float* mc = merge + (size_t)mrow0 * 256 + j;
    #pragma unroll 4
    for (int m = 0; m < 256; ++m)
        acc = fmaf(wr[m], mc[(size_t)m * 256], acc);
    WT[(size_t)j * 512 + dd] = f2b(acc);
}

// ---------------------------------------------------------------------------
// Wall [576][512] bf16:
//   rows 0..511:   (W_x[:, :16] @ W_dt)^T   (composed dt weight)
//   rows 512..543: W_x[:, 16+(n-512)]^T     (B,C columns)
//   rows 544..575: 0
// ---------------------------------------------------------------------------
__global__ __launch_bounds__(256)
void wallT(const float* __restrict__ Wx, const float* __restrict__ Wdt,
           ushort* __restrict__ WT)
{
    int idx = blockIdx.x * 256 + threadIdx.x;   // n*64 + kg
    int n = idx >> 6, kg = idx & 63;
    s16x8 v;
    #pragma unroll
    for (int i = 0; i < 8; ++i) {
        int k = kg * 8 + i;
        float acc = 0.f;
        if (n < 512) {
            #pragma unroll
            for (int j = 0; j < 16; ++j)
                acc = fmaf(Wx[k * 48 + j], Wdt[j * 512 + n], acc);
        } else if (n < 544) {
            acc = Wx[k * 48 + 16 + (n - 512)];
        }
        v[i] = (short)f2b(acc);
    }
    *reinterpret_cast<s16x8*>(WT + (size_t)n * 512 + kg * 8) = v;
}

// ---------------------------------------------------------------------------
// bf16 MFMA GEMM, m97 structure: global_load_lds staging, single-buffer
// 2-barrier K-loop, XOR-swizzled LDS (linear dest + inv-swz source + swz read).
// C = sum_seg A_seg(bf16 MxKT, opt row-flip) @ BT_seg([N][KT])^T
// 4 waves 2x2, wave tile (BM/2)x(BN/2), 16x16x32 frags, BK=64.
// KT compile-time; K-loop and seg-loop fully unrolled so all gl16/ds_read
// addresses fold to base+imm (kills VALU address math -- R6 VALUBusy 56%).
// EPI: 0 = f32 store, 1 = bf16 store,
//      2 = col<512: dt=softplus(acc+bias[c]); col 512..543: xd; else skip.
// ---------------------------------------------------------------------------
template<int BM, int BN, int KT, int EPI, int ZMODE, int NSEG>
__global__ __launch_bounds__(256)
void mgemm(const ushort* __restrict__ A0, const ushort* __restrict__ A1,
           const ushort* __restrict__ B0, const ushort* __restrict__ B1,
           void* __restrict__ C0, void* __restrict__ C1,
           const float* __restrict__ bias0, const float* __restrict__ bias1,
           float* __restrict__ X0, float* __restrict__ X1,
           int ldc, int flip0, int flip1)
{
    constexpr int MF = BM / 32, NF = BN / 32;
    constexpr int ABYTES = BM * 128;
    __shared__ char lds[BM * 128 + BN * 128];

    const int tid = threadIdx.x;
    const int L = tid & 63, w = tid >> 6;
    const int wm = w >> 1, wn = w & 1;
    const int m0 = blockIdx.y * BM, n0 = blockIdx.x * BN;

    f32x4 acc[MF][NF];
    #pragma unroll
    for (int i = 0; i < MF; ++i)
        #pragma unroll
        for (int j = 0; j < NF; ++j)
            acc[i][j] = (f32x4){0.f, 0.f, 0.f, 0.f};

    const int rsub = L >> 3;               // row within 8-row stripe
    const int q = (L & 7) ^ rsub;          // inverse-swizzled source slot

    #pragma unroll
    for (int si = 0; si < (ZMODE ? 1 : NSEG); ++si) {
        const int s = ZMODE ? blockIdx.z : si;
        const ushort* Ap = s ? A1 : A0;
        const ushort* Bp = s ? B1 : B0;
        const int flip = s ? flip1 : flip0;
        // base pointers for this block's panels (row stride KT is constant)
        #pragma unroll
        for (int k0 = 0; k0 < KT; k0 += 64) {
            #pragma unroll
            for (int c = 0; c < BM / 32; ++c) {
                int stripe = w * (BM / 32) + c;
                int rg = m0 + stripe * 8 + rsub;
                if (flip) rg ^= (T_SEQ - 1);
                gl16(Ap + (size_t)rg * KT + k0 + q * 8, lds + stripe * 1024);
            }
            #pragma unroll
            for (int c = 0; c < BN / 32; ++c) {
                int stripe = w * (BN / 32) + c;
                int ng = n0 + stripe * 8 + rsub;
                gl16(Bp + (size_t)ng * KT + k0 + q * 8, lds + ABYTES + stripe * 1024);
            }
            __syncthreads();   // compiler drains vmcnt(0) before barrier
            #pragma unroll
            for (int kk = 0; kk < 2; ++kk) {
                const int sw = (((kk * 4 + (L >> 4)) ^ (L & 7)) << 4);
                s16x8 af[MF], bf[NF];
                #pragma unroll
                for (int i = 0; i < MF; ++i) {
                    int R = wm * (BM / 2) + i * 16 + (L & 15);
                    af[i] = *reinterpret_cast<const s16x8*>(lds + R * 128 + sw);
                }
                #pragma unroll
                for (int j = 0; j < NF; ++j) {
                    int R = wn * (BN / 2) + j * 16 + (L & 15);
                    bf[j] = *reinterpret_cast<const s16x8*>(lds + ABYTES + R * 128 + sw);
                }
                #pragma unroll
                for (int i = 0; i < MF; ++i)
                    #pragma unroll
                    for (int j = 0; j < NF; ++j)
                        acc[i][j] = __builtin_amdgcn_mfma_f32_16x16x32_bf16(
                            af[i], bf[j], acc[i][j], 0, 0, 0);
            }
            __syncthreads();
        }
    }

    void* Cv = (ZMODE && blockIdx.z) ? C1 : C0;
    const float* bias = (ZMODE && blockIdx.z) ? bias1 : bias0;
    float* Xv = (ZMODE && blockIdx.z) ? X1 : X0;
    #pragma unroll
    for (int i = 0; i < MF; ++i) {
        #pragma unroll
        for (int j = 0; j < NF; ++j) {
            int r0 = m0 + wm * (BM / 2) + i * 16 + ((L >> 4) << 2);
            int c  = n0 + wn * (BN / 2) + j * 16 + (L & 15);
            if (EPI == 2) {
                if (c < 512) {
                    float bv = bias[c];
                    #pragma unroll
                    for (int r = 0; r < 4; ++r)
                        ((float*)Cv)[(size_t)(r0 + r) * 512 + c] =
                            softplusf(acc[i][j][r] + bv);
                } else if (c < 544) {
                    #pragma unroll
                    for (int r = 0; r < 4; ++r)
                        Xv[(size_t)(r0 + r) * 32 + (c - 512)] = acc[i][j][r];
                }
            } else {
                #pragma unroll
                for (int r = 0; r < 4; ++r) {
                    size_t o = (size_t)(r0 + r) * ldc + c;
                    if (EPI == 1) ((ushort*)Cv)[o] = f2b(acc[i][j][r]);
                    else          ((float*)Cv)[o]  = acc[i][j][r];
                }
            }
        }
    }
}

// ---------------------------------------------------------------------------
// Causal depthwise conv (4 taps) + bias + silu, bf16 in/out, 8 rows/thread.
// ---------------------------------------------------------------------------
__global__ __launch_bounds__(256)
void conv_kernel(const ushort* __restrict__ xz_f, const ushort* __restrict__ xz_b,
                 const float* __restrict__ w_f, const float* __restrict__ w_b,
                 const float* __restrict__ bias_f, const float* __restrict__ bias_b,
                 ushort* __restrict__ xi_f, ushort* __restrict__ xi_b)
{
    int gid = blockIdx.x;
    int dir = gid >> 11;
    const ushort* xz  = dir ? xz_b : xz_f;
    const float*  w   = dir ? w_b : w_f;
    const float*  bia = dir ? bias_b : bias_f;
    ushort*       xi  = dir ? xi_b : xi_f;

    int idx = (gid & 2047) * 256 + threadIdx.x;   // rb*512 + d
    int rb = idx >> 9, d = idx & 511;
    int r0 = rb * 8;
    int t0 = r0 & (T_SEQ - 1);
    float w0 = w[d * 4 + 0], w1 = w[d * 4 + 1], w2 = w[d * 4 + 2], w3 = w[d * 4 + 3];
    float bs = bia[d];

    float xv[11];
    #pragma unroll
    for (int k = 0; k < 11; ++k) {
        int tt = t0 - 3 + k;
        xv[k] = (tt >= 0) ? b2f(xz[(size_t)(r0 - 3 + k) * 1024 + d]) : 0.f;
    }
    #pragma unroll
    for (int j = 0; j < 8; ++j) {
        float acc = bs;
        acc = fmaf(w0, xv[j + 0], acc);
        acc = fmaf(w1, xv[j + 1], acc);
        acc = fmaf(w2, xv[j + 2], acc);
        acc = fmaf(w3, xv[j + 3], acc);
        xi[(size_t)(r0 + j) * 512 + d] = f2b(siluf(acc));
    }
}

// ---------------------------------------------------------------------------
// Chunked scan.  Thread owns channel d (16 states in regs); dt precomputed.
// bid = ((db*NCHUNK + chunk)*2 + half); d = half*256 + tid.
// Fast path: a[n] == (n+1)*a[0]  =>  dA_n = q^(n+1), q = exp(dt*a0).
// ---------------------------------------------------------------------------
__device__ __forceinline__ void scan_head(int bid, int tid,
    int& db, int& b, int& dir, int& chunk, int& d, size_t& row0)
{
    int half = bid & 1;
    int tmp = bid >> 1;
    chunk = tmp & (NCHUNK - 1);
    db = tmp >> 7;
    b = db & 1; dir = db >> 1;
    d = half * 256 + tid;
    row0 = (size_t)b * T_SEQ + (size_t)chunk * CLEN;
}

__device__ __forceinline__ void load_a16(const float* __restrict__ Al, int d,
                                         float* a, bool& fast)
{
    const float4* ap = reinterpret_cast<const float4*>(Al + (size_t)d * 16);
    #pragma unroll
    for (int i = 0; i < 4; ++i) {
        float4 v = ap[i];
        a[4*i+0] = -expf(v.x); a[4*i+1] = -expf(v.y);
        a[4*i+2] = -expf(v.z); a[4*i+3] = -expf(v.w);
    }
    fast = true;
    #pragma unroll
    for (int n = 1; n < 16; ++n)
        fast = fast && (fabsf(a[n] - (float)(n + 1) * a[0]) <= 1e-4f * (float)(n + 1));
}

#define LD16(dst, src_t)                                              \
    {                                                                 \
        const float4* q_ = reinterpret_cast<const float4*>(src_t);    \
        float4 q0 = q_[0], q1 = q_[1], q2 = q_[2], q3 = q_[3];        \
        dst[0]=q0.x; dst[1]=q0.y; dst[2]=q0.z; dst[3]=q0.w;           \
        dst[4]=q1.x; dst[5]=q1.y; dst[6]=q1.z; dst[7]=q1.w;           \
        dst[8]=q2.x; dst[9]=q2.y; dst[10]=q2.z; dst[11]=q2.w;         \
        dst[12]=q3.x; dst[13]=q3.y; dst[14]=q3.z; dst[15]=q3.w;       \
    }

__global__ __launch_bounds__(256)
void scan_pass1(const ushort* __restrict__ xi_f, const ushort* __restrict__ xi_b,
                const float* __restrict__ dt_f, const float* __restrict__ dt_b,
                const float* __restrict__ xd_f, const float* __restrict__ xd_b,
                const float* __restrict__ Al_f, const float* __restrict__ Al_b,
                float* __restrict__ Acum, float* __restrict__ Hloc)
{
    __shared__ float Bsh[CLEN][16];
    int db, b, dir, chunk, d; size_t row0;
    scan_head(blockIdx.x, threadIdx.x, db, b, dir, chunk, d, row0);

    const ushort* xi = dir ? xi_b : xi_f;
    const float* dt  = dir ? dt_b : dt_f;
    const float* xd  = dir ? xd_b : xd_f;
    const float* Al  = dir ? Al_b : Al_f;

    float a[16]; bool fast;
    load_a16(Al, d, a, fast);

    for (int i = threadIdx.x; i < CLEN * 16; i += 256) {
        int r = i >> 4, n = i & 15;
        Bsh[r][n] = xd[(row0 + r) * 32 + n];
    }
    __syncthreads();

    const ushort* xip = xi + row0 * 512 + d;
    const float*  dtp = dt + row0 * 512 + d;
    float h[16] = {};
    float sumdt = 0.f;

    if (fast) {
        #pragma unroll 2
        for (int t = 0; t < CLEN; ++t) {
            float bn[16]; LD16(bn, Bsh[t]);
            float dtv = dtp[(size_t)t * 512];
            float xiv = b2f(xip[(size_t)t * 512]);
            float dbx = dtv * xiv;
            sumdt += dtv;
            float qv = __expf(dtv * a[0]);
            float dA = qv;
            #pragma unroll
            for (int n = 0; n < 16; ++n) {
                h[n] = fmaf(dA, h[n], dbx * bn[n]);
                dA *= qv;
            }
        }
    } else {
        #pragma unroll 2
        for (int t = 0; t < CLEN; ++t) {
            float bn[16]; LD16(bn, Bsh[t]);
            float dtv = dtp[(size_t)t * 512];
            float xiv = b2f(xip[(size_t)t * 512]);
            float dbx = dtv * xiv;
            sumdt += dtv;
            #pragma unroll
            for (int n = 0; n < 16; ++n) {
                float dA = __expf(dtv * a[n]);
                h[n] = fmaf(dA, h[n], dbx * bn[n]);
            }
        }
    }

    size_t si = ((size_t)((db * NCHUNK + chunk) * 512 + d)) * 16;
    float4* Ao = reinterpret_cast<float4*>(Acum + si);
    float4* Ho = reinterpret_cast<float4*>(Hloc + si);
    #pragma unroll
    for (int i = 0; i < 4; ++i) {
        Ao[i] = make_float4(__expf(a[4*i+0]*sumdt), __expf(a[4*i+1]*sumdt),
                            __expf(a[4*i+2]*sumdt), __expf(a[4*i+3]*sumdt));
        Ho[i] = make_float4(h[4*i+0], h[4*i+1], h[4*i+2], h[4*i+3]);
    }
}

__global__ __launch_bounds__(256)
void scan_pass2(const float* __restrict__ Acum, const float* __restrict__ Hloc,
                float* __restrict__ Hin)
{
    int tid = blockIdx.x * 256 + threadIdx.x;
    int db = tid >> 13;
    int dn = tid & 8191;
    size_t base = (size_t)db * NCHUNK * 8192 + dn;
    float h = 0.f;
    #pragma unroll 8
    for (int c = 0; c < NCHUNK; ++c) {
        size_t si = base + (size_t)c * 8192;
        Hin[si] = h;
        h = fmaf(Acum[si], h, Hloc[si]);
    }
}

__global__ __launch_bounds__(256)
void scan_pass3(const ushort* __restrict__ xi_f, const ushort* __restrict__ xi_b,
                const float* __restrict__ dt_f, const float* __restrict__ dt_b,
                const float* __restrict__ xd_f, const float* __restrict__ xd_b,
                const float* __restrict__ Al_f, const float* __restrict__ Al_b,
                const ushort* __restrict__ xz_f, const ushort* __restrict__ xz_b,
                const float* __restrict__ D_f, const float* __restrict__ D_b,
                const float* __restrict__ Hin,
                ushort* __restrict__ y_f, ushort* __restrict__ y_b)
{
    __shared__ float Bsh[CLEN][16];
    __shared__ float Csh[CLEN][16];
    int db, b, dir, chunk, d; size_t row0;
    scan_head(blockIdx.x, threadIdx.x, db, b, dir, chunk, d, row0);

    const ushort* xi = dir ? xi_b : xi_f;
    const float* dt  = dir ? dt_b : dt_f;
    const float* xd  = dir ? xd_b : xd_f;
    const float* Al  = dir ? Al_b : Al_f;
    const ushort* xz = dir ? xz_b : xz_f;
    const float* Dv  = dir ? D_b  : D_f;
    ushort*      y   = dir ? y_b  : y_f;

    float a[16]; bool fast;
    load_a16(Al, d, a, fast);
    float Dd = Dv[d];

    for (int i = threadIdx.x; i < CLEN * 32; i += 256) {
        int r = i >> 5, c = i & 31;
        float v = xd[(row0 + r) * 32 + c];
        if (c < 16) Bsh[r][c] = v; else Csh[r][c - 16] = v;
    }
    __syncthreads();

    float h[16];
    {
        size_t si = ((size_t)((db * NCHUNK + chunk) * 512 + d)) * 16;
        const float4* hp = reinterpret_cast<const float4*>(Hin + si);
        #pragma unroll
        for (int i = 0; i < 4; ++i) {
            float4 v = hp[i];
            h[4*i+0] = v.x; h[4*i+1] = v.y; h[4*i+2] = v.z; h[4*i+3] = v.w;
        }
    }

    const ushort* xip = xi + row0 * 512 + d;
    const float*  dtp = dt + row0 * 512 + d;
    const ushort* zp  = xz + row0 * 1024 + 512 + d;
    ushort*       yp  = y  + row0 * 512 + d;

    if (fast) {
        #pragma unroll 2
        for (int t = 0; t < CLEN; ++t) {
            float bn[16]; LD16(bn, Bsh[t]);
            float cn[16]; LD16(cn, Csh[t]);
            float dtv = dtp[(size_t)t * 512];
            float xiv = b2f(xip[(size_t)t * 512]);
            float zv  = b2f(zp[(size_t)t * 1024]);
            float dbx = dtv * xiv;
            float qv = __expf(dtv * a[0]);
            float dA = qv;
            float yacc = 0.f;
            #pragma unroll
            for (int n = 0; n < 16; ++n) {
                h[n] = fmaf(dA, h[n], dbx * bn[n]);
                yacc = fmaf(h[n], cn[n], yacc);
                dA *= qv;
            }
            yp[(size_t)t * 512] = f2b(fmaf(xiv, Dd, yacc) * siluf(zv));
        }
    } else {
        #pragma unroll 2
        for (int t = 0; t < CLEN; ++t) {
            float bn[16]; LD16(bn, Bsh[t]);
            float cn[16]; LD16(cn, Csh[t]);
            float dtv = dtp[(size_t)t * 512];
            float xiv = b2f(xip[(size_t)t * 512]);
            float zv  = b2f(zp[(size_t)t * 1024]);
            float dbx = dtv * xiv;
            float yacc = 0.f;
            #pragma unroll
            for (int n = 0; n < 16; ++n) {
                float dA = __expf(dtv * a[n]);
                h[n] = fmaf(dA, h[n], dbx * bn[n]);
                yacc = fmaf(h[n], cn[n], yacc);
            }
            yp[(size_t)t * 512] = f2b(fmaf(xiv, Dd, yacc) * siluf(zv));
        }
    }
}

// ---------------------------------------------------------------------------
extern "C" void kernel_launch(void* const* d_in, const int* in_sizes, int n_in,
                              void* d_out, int out_size, void* d_ws, size_t ws_size,
                              hipStream_t stream)
{
    const float* x       = (const float*)d_in[0];
    const float* fW_in   = (const float*)d_in[1];
    const float* fconv_w = (const float*)d_in[2];
    const float* fconv_b = (const float*)d_in[3];
    const float* fW_x    = (const float*)d_in[4];
    const float* fW_dt   = (const float*)d_in[5];
    const float* fb_dt   = (const float*)d_in[6];
    const float* fA_log  = (const float*)d_in[7];
    const float* fD      = (const float*)d_in[8];
    const float* fW_out  = (const float*)d_in[9];
    const float* bW_in   = (const float*)d_in[10];
    const float* bconv_w = (const float*)d_in[11];
    const float* bconv_b = (const float*)d_in[12];
    const float* bW_x    = (const float*)d_in[13];
    const float* bW_dt   = (const float*)d_in[14];
    const float* bb_dt   = (const float*)d_in[15];
    const float* bA_log  = (const float*)d_in[16];
    const float* bD      = (const float*)d_in[17];
    const float* bW_out  = (const float*)d_in[18];
    const float* merge   = (const float*)d_in[19];
    float* out = (float*)d_out;

    char* ws = (char*)d_ws;
    ushort* xbh     = (ushort*)ws; ws += (size_t)ROWS * 256 * 2;
    ushort* WinT_f  = (ushort*)ws; ws += (size_t)1024 * 256 * 2;
    ushort* WinT_b  = (ushort*)ws; ws += (size_t)1024 * 256 * 2;
    ushort* WfT     = (ushort*)ws; ws += (size_t)256 * 512 * 2;
    ushort* WbT     = (ushort*)ws; ws += (size_t)256 * 512 * 2;
    ushort* Wall_f  = (ushort*)ws; ws += (size_t)576 * 512 * 2;
    ushort* Wall_b  = (ushort*)ws; ws += (size_t)576 * 512 * 2;
    ushort* xz_f    = (ushort*)ws; ws += (size_t)ROWS * 1024 * 2;
    ushort* xz_b    = (ushort*)ws; ws += (size_t)ROWS * 1024 * 2;
    ushort* xi_f    = (ushort*)ws; ws += (size_t)ROWS * 512 * 2;
    ushort* xi_b    = (ushort*)ws; ws += (size_t)ROWS * 512 * 2;
    ushort* y_f     = (ushort*)ws; ws += (size_t)ROWS * 512 * 2;
    ushort* y_b     = (ushort*)ws; ws += (size_t)ROWS * 512 * 2;
    float*  dt_f    = (float*)ws;  ws += (size_t)ROWS * 512 * 4;
    float*  dt_b    = (float*)ws;  ws += (size_t)ROWS * 512 * 4;
    float*  xd_f    = (float*)ws;  ws += (size_t)ROWS * 32 * 4;
    float*  xd_b    = (float*)ws;  ws += (size_t)ROWS * 32 * 4;
    float*  Acum    = (float*)ws;  ws += (size_t)4 * NCHUNK * 8192 * 4;
    float*  Hloc    = (float*)ws;  ws += (size_t)4 * NCHUNK * 8192 * 4;
    float*  Hin     = (float*)ws;  ws += (size_t)4 * NCHUNK * 8192 * 4;

    dim3 blk(256);

    // prep
    cvt_bf16<<<1024, blk, 0, stream>>>(x, xbh);
    transpose_w<<<128, blk, 0, stream>>>(fW_in, WinT_f, 256, 1024);
    transpose_w<<<128, blk, 0, stream>>>(bW_in, WinT_b, 256, 1024);
    fusewT<<<512, blk, 0, stream>>>(fW_out, merge, WfT, 0);
    fusewT<<<512, blk, 0, stream>>>(bW_out, merge, WbT, 256);
    wallT<<<144, blk, 0, stream>>>(fW_x, fW_dt, Wall_f);
    wallT<<<144, blk, 0, stream>>>(bW_x, bW_dt, Wall_b);

    // G1: xz = x @ W_in, both dirs (z picks dir; bw flips rows)  K=256
    mgemm<128, 128, 256, 1, 1, 1><<<dim3(8, 64, 2), blk, 0, stream>>>(
        xbh, xbh, WinT_f, WinT_b, xz_f, xz_b, nullptr, nullptr, nullptr, nullptr,
        1024, 0, 1);

    // conv + silu (both dirs)
    conv_kernel<<<4096, blk, 0, stream>>>(xz_f, xz_b, fconv_w, bconv_w,
                                          fconv_b, bconv_b, xi_f, xi_b);

    // dt+xd merged: [dt | xd | pad] = xi @ Wall^T ; softplus epilogue. K=512
    mgemm<128, 192, 512, 2, 1, 1><<<dim3(3, 64, 2), blk, 0, stream>>>(
        xi_f, xi_b, Wall_f, Wall_b, dt_f, dt_b, fb_dt, bb_dt, xd_f, xd_b,
        512, 0, 0);

    // chunked scan
    scan_pass1<<<1024, blk, 0, stream>>>(xi_f, xi_b, dt_f, dt_b, xd_f, xd_b,
                                         fA_log, bA_log, Acum, Hloc);
    scan_pass2<<<128, blk, 0, stream>>>(Acum, Hloc, Hin);
    scan_pass3<<<1024, blk, 0, stream>>>(xi_f, xi_b, dt_f, dt_b, xd_f, xd_b,
                                         fA_log, bA_log, xz_f, xz_b, fD, bD,
                                         Hin, y_f, y_b);

    // G5: out = y_f @ WfT^T + flip(y_b) @ WbT^T  (segs unrolled)  K=512
    mgemm<128, 64, 512, 0, 0, 2><<<dim3(4, 64, 1), blk, 0, stream>>>(
        y_f, y_b, WfT, WbT, out, out, nullptr, nullptr, nullptr, nullptr,
        256, 0, 1);
}

// Round 8
// 210.133 us; speedup vs baseline: 1.4405x; 1.4405x over previous
//
#include <hip/hip_runtime.h>
#include <math.h>

#define T_SEQ 4096
#define ROWS 8192
#define NCHUNK 128
#define CLEN 32

typedef __attribute__((ext_vector_type(4))) float f32x4;
typedef __attribute__((ext_vector_type(8))) short s16x8;

__device__ __forceinline__ float siluf(float x) { return x / (1.f + __expf(-x)); }
__device__ __forceinline__ float softplusf(float x) {
    return fmaxf(x, 0.f) + __logf(1.f + __expf(-fabsf(x)));
}
__device__ __forceinline__ ushort f2b(float f) {
    uint u = __float_as_uint(f);
    u += 0x7fffu + ((u >> 16) & 1u);
    return (ushort)(u >> 16);
}
__device__ __forceinline__ float b2f(ushort h) { return __uint_as_float(((uint)h) << 16); }

// direct global->LDS, 16B per lane.  LDS dest is wave-uniform base + lane*16;
// global src is per-lane.
__device__ __forceinline__ void gl16(const ushort* g, const char* l)
{
    __builtin_amdgcn_global_load_lds(
        (const __attribute__((address_space(1))) void*)g,
        (__attribute__((address_space(3))) void*)l,
        16, 0, 0);
}

// ---------------------------------------------------------------------------
// fp32 -> bf16 bulk convert (8 elems/thread)
// ---------------------------------------------------------------------------
__global__ __launch_bounds__(256)
void cvt_bf16(const float* __restrict__ in, ushort* __restrict__ out)
{
    int i = blockIdx.x * 256 + threadIdx.x;
    const float4* p = reinterpret_cast<const float4*>(in) + (size_t)i * 2;
    float4 a = p[0], b = p[1];
    s16x8 v;
    v[0] = (short)f2b(a.x); v[1] = (short)f2b(a.y); v[2] = (short)f2b(a.z); v[3] = (short)f2b(a.w);
    v[4] = (short)f2b(b.x); v[5] = (short)f2b(b.y); v[6] = (short)f2b(b.z); v[7] = (short)f2b(b.w);
    *reinterpret_cast<s16x8*>(out + (size_t)i * 8) = v;
}

// ---------------------------------------------------------------------------
// W [Kdim][Ndim] fp32 -> WT [Ndim][Kdim] bf16
// ---------------------------------------------------------------------------
__global__ __launch_bounds__(256)
void transpose_w(const float* __restrict__ W, ushort* __restrict__ WT, int Kdim, int Ndim)
{
    int idx = blockIdx.x * 256 + threadIdx.x;
    int kg8 = Kdim >> 3;
    if (idx >= Ndim * kg8) return;
    int n = idx / kg8, kg = idx - n * kg8;
    s16x8 v;
    #pragma unroll
    for (int i = 0; i < 8; ++i)
        v[i] = (short)f2b(W[(size_t)(kg * 8 + i) * Ndim + n]);
    *reinterpret_cast<s16x8*>(WT + (size_t)n * Kdim + kg * 8) = v;
}

// ---------------------------------------------------------------------------
// Fused+transposed output weights: WT[j][d] = sum_m W_out[d][m]*merge[mrow0+m][j]
// ---------------------------------------------------------------------------
__global__ __launch_bounds__(256)
void fusewT(const float* __restrict__ W_out, const float* __restrict__ merge,
            ushort* __restrict__ WT, int mrow0)
{
    int idx = blockIdx.x * 256 + threadIdx.x;   // d*256 + j
    int dd = idx >> 8, j = idx & 255;
    float acc = 0.f;
    const float* wr = W_out + dd * 256;
    const float* mc = merge + (size_t)mrow0 * 256 + j;
    #pragma unroll 4
    for (int m = 0; m < 256; ++m)
        acc = fmaf(wr[m], mc[(size_t)m * 256], acc);
    WT[(size_t)j * 512 + dd] = f2b(acc);
}

// ---------------------------------------------------------------------------
// Wall [640][512] bf16:
//   rows 0..511:   (W_x[:, :16] @ W_dt)^T   (composed dt weight)
//   rows 512..543: W_x[:, 16+(n-512)]^T     (B,C columns)
//   rows 544..639: 0  (pad to 5x128 tiles)
// ---------------------------------------------------------------------------
__global__ __launch_bounds__(256)
void wallT(const float* __restrict__ Wx, const float* __restrict__ Wdt,
           ushort* __restrict__ WT)
{
    int idx = blockIdx.x * 256 + threadIdx.x;   // n*64 + kg
    int n = idx >> 6, kg = idx & 63;
    s16x8 v;
    #pragma unroll
    for (int i = 0; i < 8; ++i) {
        int k = kg * 8 + i;
        float acc = 0.f;
        if (n < 512) {
            #pragma unroll
            for (int j = 0; j < 16; ++j)
                acc = fmaf(Wx[k * 48 + j], Wdt[j * 512 + n], acc);
        } else if (n < 544) {
            acc = Wx[k * 48 + 16 + (n - 512)];
        }
        v[i] = (short)f2b(acc);
    }
    *reinterpret_cast<s16x8*>(WT + (size_t)n * 512 + kg * 8) = v;
}

// ---------------------------------------------------------------------------
// bf16 MFMA GEMM, m97 structure: global_load_lds staging, single-buffer
// 2-barrier RUNTIME K-loop (R7 post-mortem: full unroll kills occupancy),
// XOR-swizzled LDS (linear dest + inv-swz source + swz read).
// Per-stripe global pointers strength-reduced: init once, +64 elems/step.
// C = sum_seg A_seg(bf16 MxK, opt row-flip) @ BT_seg([N][K])^T
// 4 waves 2x2, wave tile (BM/2)x(BN/2), 16x16x32 frags, BK=64.
// EPI: 0 = f32 store, 1 = bf16 store,
//      2 = col<512: dt=softplus(acc+bias[c]); col 512..543: xd; else skip.
// ---------------------------------------------------------------------------
template<int BM, int BN, int EPI>
__global__ __launch_bounds__(256)
void mgemm(const ushort* __restrict__ A0, const ushort* __restrict__ A1,
           const ushort* __restrict__ B0, const ushort* __restrict__ B1,
           void* __restrict__ C0, void* __restrict__ C1,
           const float* __restrict__ bias0, const float* __restrict__ bias1,
           float* __restrict__ X0, float* __restrict__ X1,
           int K, int ldc, int flip0, int flip1, int zmode, int nseg)
{
    constexpr int MF = BM / 32, NF = BN / 32;
    constexpr int ASTR = BM / 32, BSTR = BN / 32;   // gl16 stripes per thread
    constexpr int ABYTES = BM * 128;
    __shared__ char lds[BM * 128 + BN * 128];

    const int tid = threadIdx.x;
    const int L = tid & 63, w = tid >> 6;
    const int wm = w >> 1, wn = w & 1;
    const int m0 = blockIdx.y * BM, n0 = blockIdx.x * BN;

    f32x4 acc[MF][NF];
    #pragma unroll
    for (int i = 0; i < MF; ++i)
        #pragma unroll
        for (int j = 0; j < NF; ++j)
            acc[i][j] = (f32x4){0.f, 0.f, 0.f, 0.f};

    const int rsub = L >> 3;               // row within 8-row stripe
    const int q = (L & 7) ^ rsub;          // inverse-swizzled source slot
    const int sb = zmode ? blockIdx.z : 0;
    const int se = zmode ? sb + 1 : nseg;

    for (int s = sb; s < se; ++s) {
        const ushort* Ap = s ? A1 : A0;
        const ushort* Bp = s ? B1 : B0;
        const int flip = s ? flip1 : flip0;

        // per-stripe per-lane pointers, strength-reduced over K
        const ushort* ap[ASTR];
        const ushort* bp[BSTR];
        #pragma unroll
        for (int c = 0; c < ASTR; ++c) {
            int rg = m0 + (w * ASTR + c) * 8 + rsub;
            if (flip) rg ^= (T_SEQ - 1);
            ap[c] = Ap + (size_t)rg * K + q * 8;
        }
        #pragma unroll
        for (int c = 0; c < BSTR; ++c) {
            int ng = n0 + (w * BSTR + c) * 8 + rsub;
            bp[c] = Bp + (size_t)ng * K + q * 8;
        }

        for (int k0 = 0; k0 < K; k0 += 64) {
            #pragma unroll
            for (int c = 0; c < ASTR; ++c) {
                gl16(ap[c], lds + (w * ASTR + c) * 1024);
                ap[c] += 64;
            }
            #pragma unroll
            for (int c = 0; c < BSTR; ++c) {
                gl16(bp[c], lds + ABYTES + (w * BSTR + c) * 1024);
                bp[c] += 64;
            }
            __syncthreads();   // compiler drains vmcnt(0) before barrier
            #pragma unroll
            for (int kk = 0; kk < 2; ++kk) {
                const int sw = (((kk * 4 + (L >> 4)) ^ (L & 7)) << 4);
                s16x8 af[MF], bf[NF];
                #pragma unroll
                for (int i = 0; i < MF; ++i) {
                    int R = wm * (BM / 2) + i * 16 + (L & 15);
                    af[i] = *reinterpret_cast<const s16x8*>(lds + R * 128 + sw);
                }
                #pragma unroll
                for (int j = 0; j < NF; ++j) {
                    int R = wn * (BN / 2) + j * 16 + (L & 15);
                    bf[j] = *reinterpret_cast<const s16x8*>(lds + ABYTES + R * 128 + sw);
                }
                #pragma unroll
                for (int i = 0; i < MF; ++i)
                    #pragma unroll
                    for (int j = 0; j < NF; ++j)
                        acc[i][j] = __builtin_amdgcn_mfma_f32_16x16x32_bf16(
                            af[i], bf[j], acc[i][j], 0, 0, 0);
            }
            __syncthreads();
        }
    }

    void* Cv = (zmode && blockIdx.z) ? C1 : C0;
    const float* bias = (zmode && blockIdx.z) ? bias1 : bias0;
    float* Xv = (zmode && blockIdx.z) ? X1 : X0;
    #pragma unroll
    for (int i = 0; i < MF; ++i) {
        #pragma unroll
        for (int j = 0; j < NF; ++j) {
            int r0 = m0 + wm * (BM / 2) + i * 16 + ((L >> 4) << 2);
            int c  = n0 + wn * (BN / 2) + j * 16 + (L & 15);
            if (EPI == 2) {
                if (c < 512) {
                    float bv = bias[c];
                    #pragma unroll
                    for (int r = 0; r < 4; ++r)
                        ((float*)Cv)[(size_t)(r0 + r) * 512 + c] =
                            softplusf(acc[i][j][r] + bv);
                } else if (c < 544) {
                    #pragma unroll
                    for (int r = 0; r < 4; ++r)
                        Xv[(size_t)(r0 + r) * 32 + (c - 512)] = acc[i][j][r];
                }
            } else {
                #pragma unroll
                for (int r = 0; r < 4; ++r) {
                    size_t o = (size_t)(r0 + r) * ldc + c;
                    if (EPI == 1) ((ushort*)Cv)[o] = f2b(acc[i][j][r]);
                    else          ((float*)Cv)[o]  = acc[i][j][r];
                }
            }
        }
    }
}

// ---------------------------------------------------------------------------
// Causal depthwise conv (4 taps) + bias + silu, bf16 in/out, 8 rows/thread.
// ---------------------------------------------------------------------------
__global__ __launch_bounds__(256)
void conv_kernel(const ushort* __restrict__ xz_f, const ushort* __restrict__ xz_b,
                 const float* __restrict__ w_f, const float* __restrict__ w_b,
                 const float* __restrict__ bias_f, const float* __restrict__ bias_b,
                 ushort* __restrict__ xi_f, ushort* __restrict__ xi_b)
{
    int gid = blockIdx.x;
    int dir = gid >> 11;
    const ushort* xz  = dir ? xz_b : xz_f;
    const float*  w   = dir ? w_b : w_f;
    const float*  bia = dir ? bias_b : bias_f;
    ushort*       xi  = dir ? xi_b : xi_f;

    int idx = (gid & 2047) * 256 + threadIdx.x;   // rb*512 + d
    int rb = idx >> 9, d = idx & 511;
    int r0 = rb * 8;
    int t0 = r0 & (T_SEQ - 1);
    float w0 = w[d * 4 + 0], w1 = w[d * 4 + 1], w2 = w[d * 4 + 2], w3 = w[d * 4 + 3];
    float bs = bia[d];

    float xv[11];
    #pragma unroll
    for (int k = 0; k < 11; ++k) {
        int tt = t0 - 3 + k;
        xv[k] = (tt >= 0) ? b2f(xz[(size_t)(r0 - 3 + k) * 1024 + d]) : 0.f;
    }
    #pragma unroll
    for (int j = 0; j < 8; ++j) {
        float acc = bs;
        acc = fmaf(w0, xv[j + 0], acc);
        acc = fmaf(w1, xv[j + 1], acc);
        acc = fmaf(w2, xv[j + 2], acc);
        acc = fmaf(w3, xv[j + 3], acc);
        xi[(size_t)(r0 + j) * 512 + d] = f2b(siluf(acc));
    }
}

// ---------------------------------------------------------------------------
// Chunked scan.  Thread owns channel d (16 states in regs); dt precomputed.
// bid = ((db*NCHUNK + chunk)*2 + half); d = half*256 + tid.
// Fast path: a[n] == (n+1)*a[0]  =>  dA_n = q^(n+1), q = exp(dt*a0).
// ---------------------------------------------------------------------------
__device__ __forceinline__ void scan_head(int bid, int tid,
    int& db, int& b, int& dir, int& chunk, int& d, size_t& row0)
{
    int half = bid & 1;
    int tmp = bid >> 1;
    chunk = tmp & (NCHUNK - 1);
    db = tmp >> 7;
    b = db & 1; dir = db >> 1;
    d = half * 256 + tid;
    row0 = (size_t)b * T_SEQ + (size_t)chunk * CLEN;
}

__device__ __forceinline__ void load_a16(const float* __restrict__ Al, int d,
                                         float* a, bool& fast)
{
    const float4* ap = reinterpret_cast<const float4*>(Al + (size_t)d * 16);
    #pragma unroll
    for (int i = 0; i < 4; ++i) {
        float4 v = ap[i];
        a[4*i+0] = -expf(v.x); a[4*i+1] = -expf(v.y);
        a[4*i+2] = -expf(v.z); a[4*i+3] = -expf(v.w);
    }
    fast = true;
    #pragma unroll
    for (int n = 1; n < 16; ++n)
        fast = fast && (fabsf(a[n] - (float)(n + 1) * a[0]) <= 1e-4f * (float)(n + 1));
}

#define LD16(dst, src_t)                                              \
    {                                                                 \
        const float4* q_ = reinterpret_cast<const float4*>(src_t);    \
        float4 q0 = q_[0], q1 = q_[1], q2 = q_[2], q3 = q_[3];        \
        dst[0]=q0.x; dst[1]=q0.y; dst[2]=q0.z; dst[3]=q0.w;           \
        dst[4]=q1.x; dst[5]=q1.y; dst[6]=q1.z; dst[7]=q1.w;           \
        dst[8]=q2.x; dst[9]=q2.y; dst[10]=q2.z; dst[11]=q2.w;         \
        dst[12]=q3.x; dst[13]=q3.y; dst[14]=q3.z; dst[15]=q3.w;       \
    }

__global__ __launch_bounds__(256)
void scan_pass1(const ushort* __restrict__ xi_f, const ushort* __restrict__ xi_b,
                const float* __restrict__ dt_f, const float* __restrict__ dt_b,
                const float* __restrict__ xd_f, const float* __restrict__ xd_b,
                const float* __restrict__ Al_f, const float* __restrict__ Al_b,
                float* __restrict__ Acum, float* __restrict__ Hloc)
{
    __shared__ float Bsh[CLEN][16];
    int db, b, dir, chunk, d; size_t row0;
    scan_head(blockIdx.x, threadIdx.x, db, b, dir, chunk, d, row0);

    const ushort* xi = dir ? xi_b : xi_f;
    const float* dt  = dir ? dt_b : dt_f;
    const float* xd  = dir ? xd_b : xd_f;
    const float* Al  = dir ? Al_b : Al_f;

    float a[16]; bool fast;
    load_a16(Al, d, a, fast);

    for (int i = threadIdx.x; i < CLEN * 16; i += 256) {
        int r = i >> 4, n = i & 15;
        Bsh[r][n] = xd[(row0 + r) * 32 + n];
    }
    __syncthreads();

    const ushort* xip = xi + row0 * 512 + d;
    const float*  dtp = dt + row0 * 512 + d;
    float h[16] = {};
    float sumdt = 0.f;

    if (fast) {
        #pragma unroll 2
        for (int t = 0; t < CLEN; ++t) {
            float bn[16]; LD16(bn, Bsh[t]);
            float dtv = dtp[(size_t)t * 512];
            float xiv = b2f(xip[(size_t)t * 512]);
            float dbx = dtv * xiv;
            sumdt += dtv;
            float qv = __expf(dtv * a[0]);
            float dA = qv;
            #pragma unroll
            for (int n = 0; n < 16; ++n) {
                h[n] = fmaf(dA, h[n], dbx * bn[n]);
                dA *= qv;
            }
        }
    } else {
        #pragma unroll 2
        for (int t = 0; t < CLEN; ++t) {
            float bn[16]; LD16(bn, Bsh[t]);
            float dtv = dtp[(size_t)t * 512];
            float xiv = b2f(xip[(size_t)t * 512]);
            float dbx = dtv * xiv;
            sumdt += dtv;
            #pragma unroll
            for (int n = 0; n < 16; ++n) {
                float dA = __expf(dtv * a[n]);
                h[n] = fmaf(dA, h[n], dbx * bn[n]);
            }
        }
    }

    size_t si = ((size_t)((db * NCHUNK + chunk) * 512 + d)) * 16;
    float4* Ao = reinterpret_cast<float4*>(Acum + si);
    float4* Ho = reinterpret_cast<float4*>(Hloc + si);
    #pragma unroll
    for (int i = 0; i < 4; ++i) {
        Ao[i] = make_float4(__expf(a[4*i+0]*sumdt), __expf(a[4*i+1]*sumdt),
                            __expf(a[4*i+2]*sumdt), __expf(a[4*i+3]*sumdt));
        Ho[i] = make_float4(h[4*i+0], h[4*i+1], h[4*i+2], h[4*i+3]);
    }
}

__global__ __launch_bounds__(256)
void scan_pass2(const float* __restrict__ Acum, const float* __restrict__ Hloc,
                float* __restrict__ Hin)
{
    int tid = blockIdx.x * 256 + threadIdx.x;
    int db = tid >> 13;
    int dn = tid & 8191;
    size_t base = (size_t)db * NCHUNK * 8192 + dn;
    float h = 0.f;
    #pragma unroll 8
    for (int c = 0; c < NCHUNK; ++c) {
        size_t si = base + (size_t)c * 8192;
        Hin[si] = h;
        h = fmaf(Acum[si], h, Hloc[si]);
    }
}

__global__ __launch_bounds__(256)
void scan_pass3(const ushort* __restrict__ xi_f, const ushort* __restrict__ xi_b,
                const float* __restrict__ dt_f, const float* __restrict__ dt_b,
                const float* __restrict__ xd_f, const float* __restrict__ xd_b,
                const float* __restrict__ Al_f, const float* __restrict__ Al_b,
                const ushort* __restrict__ xz_f, const ushort* __restrict__ xz_b,
                const float* __restrict__ D_f, const float* __restrict__ D_b,
                const float* __restrict__ Hin,
                ushort* __restrict__ y_f, ushort* __restrict__ y_b)
{
    __shared__ float Bsh[CLEN][16];
    __shared__ float Csh[CLEN][16];
    int db, b, dir, chunk, d; size_t row0;
    scan_head(blockIdx.x, threadIdx.x, db, b, dir, chunk, d, row0);

    const ushort* xi = dir ? xi_b : xi_f;
    const float* dt  = dir ? dt_b : dt_f;
    const float* xd  = dir ? xd_b : xd_f;
    const float* Al  = dir ? Al_b : Al_f;
    const ushort* xz = dir ? xz_b : xz_f;
    const float* Dv  = dir ? D_b  : D_f;
    ushort*      y   = dir ? y_b  : y_f;

    float a[16]; bool fast;
    load_a16(Al, d, a, fast);
    float Dd = Dv[d];

    for (int i = threadIdx.x; i < CLEN * 32; i += 256) {
        int r = i >> 5, c = i & 31;
        float v = xd[(row0 + r) * 32 + c];
        if (c < 16) Bsh[r][c] = v; else Csh[r][c - 16] = v;
    }
    __syncthreads();

    float h[16];
    {
        size_t si = ((size_t)((db * NCHUNK + chunk) * 512 + d)) * 16;
        const float4* hp = reinterpret_cast<const float4*>(Hin + si);
        #pragma unroll
        for (int i = 0; i < 4; ++i) {
            float4 v = hp[i];
            h[4*i+0] = v.x; h[4*i+1] = v.y; h[4*i+2] = v.z; h[4*i+3] = v.w;
        }
    }

    const ushort* xip = xi + row0 * 512 + d;
    const float*  dtp = dt + row0 * 512 + d;
    const ushort* zp  = xz + row0 * 1024 + 512 + d;
    ushort*       yp  = y  + row0 * 512 + d;

    if (fast) {
        #pragma unroll 2
        for (int t = 0; t < CLEN; ++t) {
            float bn[16]; LD16(bn, Bsh[t]);
            float cn[16]; LD16(cn, Csh[t]);
            float dtv = dtp[(size_t)t * 512];
            float xiv = b2f(xip[(size_t)t * 512]);
            float zv  = b2f(zp[(size_t)t * 1024]);
            float dbx = dtv * xiv;
            float qv = __expf(dtv * a[0]);
            float dA = qv;
            float yacc = 0.f;
            #pragma unroll
            for (int n = 0; n < 16; ++n) {
                h[n] = fmaf(dA, h[n], dbx * bn[n]);
                yacc = fmaf(h[n], cn[n], yacc);
                dA *= qv;
            }
            yp[(size_t)t * 512] = f2b(fmaf(xiv, Dd, yacc) * siluf(zv));
        }
    } else {
        #pragma unroll 2
        for (int t = 0; t < CLEN; ++t) {
            float bn[16]; LD16(bn, Bsh[t]);
            float cn[16]; LD16(cn, Csh[t]);
            float dtv = dtp[(size_t)t * 512];
            float xiv = b2f(xip[(size_t)t * 512]);
            float zv  = b2f(zp[(size_t)t * 1024]);
            float dbx = dtv * xiv;
            float yacc = 0.f;
            #pragma unroll
            for (int n = 0; n < 16; ++n) {
                float dA = __expf(dtv * a[n]);
                h[n] = fmaf(dA, h[n], dbx * bn[n]);
                yacc = fmaf(h[n], cn[n], yacc);
            }
            yp[(size_t)t * 512] = f2b(fmaf(xiv, Dd, yacc) * siluf(zv));
        }
    }
}

// ---------------------------------------------------------------------------
extern "C" void kernel_launch(void* const* d_in, const int* in_sizes, int n_in,
                              void* d_out, int out_size, void* d_ws, size_t ws_size,
                              hipStream_t stream)
{
    const float* x       = (const float*)d_in[0];
    const float* fW_in   = (const float*)d_in[1];
    const float* fconv_w = (const float*)d_in[2];
    const float* fconv_b = (const float*)d_in[3];
    const float* fW_x    = (const float*)d_in[4];
    const float* fW_dt   = (const float*)d_in[5];
    const float* fb_dt   = (const float*)d_in[6];
    const float* fA_log  = (const float*)d_in[7];
    const float* fD      = (const float*)d_in[8];
    const float* fW_out  = (const float*)d_in[9];
    const float* bW_in   = (const float*)d_in[10];
    const float* bconv_w = (const float*)d_in[11];
    const float* bconv_b = (const float*)d_in[12];
    const float* bW_x    = (const float*)d_in[13];
    const float* bW_dt   = (const float*)d_in[14];
    const float* bb_dt   = (const float*)d_in[15];
    const float* bA_log  = (const float*)d_in[16];
    const float* bD      = (const float*)d_in[17];
    const float* bW_out  = (const float*)d_in[18];
    const float* merge   = (const float*)d_in[19];
    float* out = (float*)d_out;

    char* ws = (char*)d_ws;
    ushort* xbh     = (ushort*)ws; ws += (size_t)ROWS * 256 * 2;
    ushort* WinT_f  = (ushort*)ws; ws += (size_t)1024 * 256 * 2;
    ushort* WinT_b  = (ushort*)ws; ws += (size_t)1024 * 256 * 2;
    ushort* WfT     = (ushort*)ws; ws += (size_t)256 * 512 * 2;
    ushort* WbT     = (ushort*)ws; ws += (size_t)256 * 512 * 2;
    ushort* Wall_f  = (ushort*)ws; ws += (size_t)640 * 512 * 2;
    ushort* Wall_b  = (ushort*)ws; ws += (size_t)640 * 512 * 2;
    ushort* xz_f    = (ushort*)ws; ws += (size_t)ROWS * 1024 * 2;
    ushort* xz_b    = (ushort*)ws; ws += (size_t)ROWS * 1024 * 2;
    ushort* xi_f    = (ushort*)ws; ws += (size_t)ROWS * 512 * 2;
    ushort* xi_b    = (ushort*)ws; ws += (size_t)ROWS * 512 * 2;
    ushort* y_f     = (ushort*)ws; ws += (size_t)ROWS * 512 * 2;
    ushort* y_b     = (ushort*)ws; ws += (size_t)ROWS * 512 * 2;
    float*  dt_f    = (float*)ws;  ws += (size_t)ROWS * 512 * 4;
    float*  dt_b    = (float*)ws;  ws += (size_t)ROWS * 512 * 4;
    float*  xd_f    = (float*)ws;  ws += (size_t)ROWS * 32 * 4;
    float*  xd_b    = (float*)ws;  ws += (size_t)ROWS * 32 * 4;
    float*  Acum    = (float*)ws;  ws += (size_t)4 * NCHUNK * 8192 * 4;
    float*  Hloc    = (float*)ws;  ws += (size_t)4 * NCHUNK * 8192 * 4;
    float*  Hin     = (float*)ws;  ws += (size_t)4 * NCHUNK * 8192 * 4;

    dim3 blk(256);

    // prep
    cvt_bf16<<<1024, blk, 0, stream>>>(x, xbh);
    transpose_w<<<128, blk, 0, stream>>>(fW_in, WinT_f, 256, 1024);
    transpose_w<<<128, blk, 0, stream>>>(bW_in, WinT_b, 256, 1024);
    fusewT<<<512, blk, 0, stream>>>(fW_out, merge, WfT, 0);
    fusewT<<<512, blk, 0, stream>>>(bW_out, merge, WbT, 256);
    wallT<<<160, blk, 0, stream>>>(fW_x, fW_dt, Wall_f);
    wallT<<<160, blk, 0, stream>>>(bW_x, bW_dt, Wall_b);

    // G1: xz = x @ W_in, both dirs (z picks dir; bw flips rows)  K=256
    mgemm<128, 128, 1><<<dim3(8, 64, 2), blk, 0, stream>>>(
        xbh, xbh, WinT_f, WinT_b, xz_f, xz_b, nullptr, nullptr, nullptr, nullptr,
        256, 1024, 0, 1, 1, 1);

    // conv + silu (both dirs)
    conv_kernel<<<4096, blk, 0, stream>>>(xz_f, xz_b, fconv_w, bconv_w,
                                          fconv_b, bconv_b, xi_f, xi_b);

    // dt+xd merged: [dt | xd | pad] = xi @ Wall^T (640 cols = 5x128 tiles)
    mgemm<128, 128, 2><<<dim3(5, 64, 2), blk, 0, stream>>>(
        xi_f, xi_b, Wall_f, Wall_b, dt_f, dt_b, fb_dt, bb_dt, xd_f, xd_b,
        512, 512, 0, 0, 1, 1);

    // chunked scan
    scan_pass1<<<1024, blk, 0, stream>>>(xi_f, xi_b, dt_f, dt_b, xd_f, xd_b,
                                         fA_log, bA_log, Acum, Hloc);
    scan_pass2<<<128, blk, 0, stream>>>(Acum, Hloc, Hin);
    scan_pass3<<<1024, blk, 0, stream>>>(xi_f, xi_b, dt_f, dt_b, xd_f, xd_b,
                                         fA_log, bA_log, xz_f, xz_b, fD, bD,
                                         Hin, y_f, y_b);

    // G5: out = y_f @ WfT^T + flip(y_b) @ WbT^T  (runtime seg loop)  K=512
    mgemm<128, 64, 0><<<dim3(4, 64, 1), blk, 0, stream>>>(
        y_f, y_b, WfT, WbT, out, out, nullptr, nullptr, nullptr, nullptr,
        512, 256, 0, 1, 0, 2);
}

// Round 9
// 200.566 us; speedup vs baseline: 1.5092x; 1.0477x over previous
//
#include <hip/hip_runtime.h>
#include <math.h>

#define T_SEQ 4096
#define ROWS 8192
#define NCHUNK 128
#define CLEN 32

typedef __attribute__((ext_vector_type(4))) float f32x4;
typedef __attribute__((ext_vector_type(8))) short s16x8;

__device__ __forceinline__ float siluf(float x) { return x / (1.f + __expf(-x)); }
__device__ __forceinline__ float softplusf(float x) {
    return fmaxf(x, 0.f) + __logf(1.f + __expf(-fabsf(x)));
}
__device__ __forceinline__ ushort f2b(float f) {
    uint u = __float_as_uint(f);
    u += 0x7fffu + ((u >> 16) & 1u);
    return (ushort)(u >> 16);
}
__device__ __forceinline__ float b2f(ushort h) { return __uint_as_float(((uint)h) << 16); }

// direct global->LDS, 16B per lane.
__device__ __forceinline__ void gl16(const ushort* g, const char* l)
{
    __builtin_amdgcn_global_load_lds(
        (const __attribute__((address_space(1))) void*)g,
        (__attribute__((address_space(3))) void*)l,
        16, 0, 0);
}

// ---------------------------------------------------------------------------
// fp32 -> bf16 bulk convert (8 elems/thread)
// ---------------------------------------------------------------------------
__global__ __launch_bounds__(256)
void cvt_bf16(const float* __restrict__ in, ushort* __restrict__ out)
{
    int i = blockIdx.x * 256 + threadIdx.x;
    const float4* p = reinterpret_cast<const float4*>(in) + (size_t)i * 2;
    float4 a = p[0], b = p[1];
    s16x8 v;
    v[0] = (short)f2b(a.x); v[1] = (short)f2b(a.y); v[2] = (short)f2b(a.z); v[3] = (short)f2b(a.w);
    v[4] = (short)f2b(b.x); v[5] = (short)f2b(b.y); v[6] = (short)f2b(b.z); v[7] = (short)f2b(b.w);
    *reinterpret_cast<s16x8*>(out + (size_t)i * 8) = v;
}

// ---------------------------------------------------------------------------
// W [Kdim][Ndim] fp32 -> WT [Ndim][Kdim] bf16
// ---------------------------------------------------------------------------
__global__ __launch_bounds__(256)
void transpose_w(const float* __restrict__ W, ushort* __restrict__ WT, int Kdim, int Ndim)
{
    int idx = blockIdx.x * 256 + threadIdx.x;
    int kg8 = Kdim >> 3;
    if (idx >= Ndim * kg8) return;
    int n = idx / kg8, kg = idx - n * kg8;
    s16x8 v;
    #pragma unroll
    for (int i = 0; i < 8; ++i)
        v[i] = (short)f2b(W[(size_t)(kg * 8 + i) * Ndim + n]);
    *reinterpret_cast<s16x8*>(WT + (size_t)n * Kdim + kg * 8) = v;
}

// ---------------------------------------------------------------------------
// Fused output weights into W_all^T [256][1024]:
//   W_allT[j][koff+dd] = sum_m W_out[dd][m] * merge[mrow0+m][j]
// ---------------------------------------------------------------------------
__global__ __launch_bounds__(256)
void fusewT(const float* __restrict__ W_out, const float* __restrict__ merge,
            ushort* __restrict__ WT, int mrow0, int koff)
{
    int idx = blockIdx.x * 256 + threadIdx.x;   // dd*256 + j
    int dd = idx >> 8, j = idx & 255;
    float acc = 0.f;
    const float* wr = W_out + dd * 256;
    const float* mc = merge + (size_t)mrow0 * 256 + j;
    #pragma unroll 4
    for (int m = 0; m < 256; ++m)
        acc = fmaf(wr[m], mc[(size_t)m * 256], acc);
    WT[(size_t)j * 1024 + koff + dd] = f2b(acc);
}

// ---------------------------------------------------------------------------
// Wall [640][512] bf16:
//   rows 0..511:   (W_x[:, :16] @ W_dt)^T   (composed dt weight)
//   rows 512..543: W_x[:, 16+(n-512)]^T     (B,C columns)
//   rows 544..639: 0  (pad to 128-col tiles)
// ---------------------------------------------------------------------------
__global__ __launch_bounds__(256)
void wallT(const float* __restrict__ Wx, const float* __restrict__ Wdt,
           ushort* __restrict__ WT)
{
    int idx = blockIdx.x * 256 + threadIdx.x;   // n*64 + kg
    int n = idx >> 6, kg = idx & 63;
    s16x8 v;
    #pragma unroll
    for (int i = 0; i < 8; ++i) {
        int k = kg * 8 + i;
        float acc = 0.f;
        if (n < 512) {
            #pragma unroll
            for (int j = 0; j < 16; ++j)
                acc = fmaf(Wx[k * 48 + j], Wdt[j * 512 + n], acc);
        } else if (n < 544) {
            acc = Wx[k * 48 + 16 + (n - 512)];
        }
        v[i] = (short)f2b(acc);
    }
    *reinterpret_cast<s16x8*>(WT + (size_t)n * 512 + kg * 8) = v;
}

// ---------------------------------------------------------------------------
// bf16 MFMA GEMM, m97 structure: global_load_lds staging, single-buffer
// 2-barrier runtime K-loop, XOR-swizzled LDS, strength-reduced pointers.
// C = sum_seg A_seg(bf16 MxK, opt row-flip) @ BT_seg([N][K])^T
// 4 waves 2x2, wave tile (BM/2)x(BN/2), 16x16x32 frags, BK=64.
// EPI: 0 = f32 store, 1 = bf16 store,
//      2 = col<512: dt=softplus(acc+bias[c]); col 512..543: xd; else skip.
// ---------------------------------------------------------------------------
template<int BM, int BN, int EPI>
__global__ __launch_bounds__(256)
void mgemm(const ushort* __restrict__ A0, const ushort* __restrict__ A1,
           const ushort* __restrict__ B0, const ushort* __restrict__ B1,
           void* __restrict__ C0, void* __restrict__ C1,
           const float* __restrict__ bias0, const float* __restrict__ bias1,
           float* __restrict__ X0, float* __restrict__ X1,
           int K, int ldc, int flip0, int flip1, int zmode, int nseg)
{
    constexpr int MF = BM / 32, NF = BN / 32;
    constexpr int ASTR = BM / 32, BSTR = BN / 32;
    constexpr int ABYTES = BM * 128;
    __shared__ char lds[BM * 128 + BN * 128];

    const int tid = threadIdx.x;
    const int L = tid & 63, w = tid >> 6;
    const int wm = w >> 1, wn = w & 1;
    const int m0 = blockIdx.y * BM, n0 = blockIdx.x * BN;

    f32x4 acc[MF][NF];
    #pragma unroll
    for (int i = 0; i < MF; ++i)
        #pragma unroll
        for (int j = 0; j < NF; ++j)
            acc[i][j] = (f32x4){0.f, 0.f, 0.f, 0.f};

    const int rsub = L >> 3;               // row within 8-row stripe
    const int q = (L & 7) ^ rsub;          // inverse-swizzled source slot
    const int sb = zmode ? blockIdx.z : 0;
    const int se = zmode ? sb + 1 : nseg;

    for (int s = sb; s < se; ++s) {
        const ushort* Ap = s ? A1 : A0;
        const ushort* Bp = s ? B1 : B0;
        const int flip = s ? flip1 : flip0;

        const ushort* ap[ASTR];
        const ushort* bp[BSTR];
        #pragma unroll
        for (int c = 0; c < ASTR; ++c) {
            int rg = m0 + (w * ASTR + c) * 8 + rsub;
            if (flip) rg ^= (T_SEQ - 1);
            ap[c] = Ap + (size_t)rg * K + q * 8;
        }
        #pragma unroll
        for (int c = 0; c < BSTR; ++c) {
            int ng = n0 + (w * BSTR + c) * 8 + rsub;
            bp[c] = Bp + (size_t)ng * K + q * 8;
        }

        for (int k0 = 0; k0 < K; k0 += 64) {
            #pragma unroll
            for (int c = 0; c < ASTR; ++c) {
                gl16(ap[c], lds + (w * ASTR + c) * 1024);
                ap[c] += 64;
            }
            #pragma unroll
            for (int c = 0; c < BSTR; ++c) {
                gl16(bp[c], lds + ABYTES + (w * BSTR + c) * 1024);
                bp[c] += 64;
            }
            __syncthreads();
            #pragma unroll
            for (int kk = 0; kk < 2; ++kk) {
                const int sw = (((kk * 4 + (L >> 4)) ^ (L & 7)) << 4);
                s16x8 af[MF], bf[NF];
                #pragma unroll
                for (int i = 0; i < MF; ++i) {
                    int R = wm * (BM / 2) + i * 16 + (L & 15);
                    af[i] = *reinterpret_cast<const s16x8*>(lds + R * 128 + sw);
                }
                #pragma unroll
                for (int j = 0; j < NF; ++j) {
                    int R = wn * (BN / 2) + j * 16 + (L & 15);
                    bf[j] = *reinterpret_cast<const s16x8*>(lds + ABYTES + R * 128 + sw);
                }
                #pragma unroll
                for (int i = 0; i < MF; ++i)
                    #pragma unroll
                    for (int j = 0; j < NF; ++j)
                        acc[i][j] = __builtin_amdgcn_mfma_f32_16x16x32_bf16(
                            af[i], bf[j], acc[i][j], 0, 0, 0);
            }
            __syncthreads();
        }
    }

    void* Cv = (zmode && blockIdx.z) ? C1 : C0;
    const float* bias = (zmode && blockIdx.z) ? bias1 : bias0;
    float* Xv = (zmode && blockIdx.z) ? X1 : X0;
    #pragma unroll
    for (int i = 0; i < MF; ++i) {
        #pragma unroll
        for (int j = 0; j < NF; ++j) {
            int r0 = m0 + wm * (BM / 2) + i * 16 + ((L >> 4) << 2);
            int c  = n0 + wn * (BN / 2) + j * 16 + (L & 15);
            if (EPI == 2) {
                if (c < 512) {
                    float bv = bias[c];
                    #pragma unroll
                    for (int r = 0; r < 4; ++r)
                        ((float*)Cv)[(size_t)(r0 + r) * 512 + c] =
                            softplusf(acc[i][j][r] + bv);
                } else if (c < 544) {
                    #pragma unroll
                    for (int r = 0; r < 4; ++r)
                        Xv[(size_t)(r0 + r) * 32 + (c - 512)] = acc[i][j][r];
                }
            } else {
                #pragma unroll
                for (int r = 0; r < 4; ++r) {
                    size_t o = (size_t)(r0 + r) * ldc + c;
                    if (EPI == 1) ((ushort*)Cv)[o] = f2b(acc[i][j][r]);
                    else          ((float*)Cv)[o]  = acc[i][j][r];
                }
            }
        }
    }
}

// ---------------------------------------------------------------------------
// Causal depthwise conv (4 taps) + bias + silu, bf16 in/out, 8 rows/thread.
// ---------------------------------------------------------------------------
__global__ __launch_bounds__(256)
void conv_kernel(const ushort* __restrict__ xz_f, const ushort* __restrict__ xz_b,
                 const float* __restrict__ w_f, const float* __restrict__ w_b,
                 const float* __restrict__ bias_f, const float* __restrict__ bias_b,
                 ushort* __restrict__ xi_f, ushort* __restrict__ xi_b)
{
    int gid = blockIdx.x;
    int dir = gid >> 11;
    const ushort* xz  = dir ? xz_b : xz_f;
    const float*  w   = dir ? w_b : w_f;
    const float*  bia = dir ? bias_b : bias_f;
    ushort*       xi  = dir ? xi_b : xi_f;

    int idx = (gid & 2047) * 256 + threadIdx.x;   // rb*512 + d
    int rb = idx >> 9, d = idx & 511;
    int r0 = rb * 8;
    int t0 = r0 & (T_SEQ - 1);
    float w0 = w[d * 4 + 0], w1 = w[d * 4 + 1], w2 = w[d * 4 + 2], w3 = w[d * 4 + 3];
    float bs = bia[d];

    float xv[11];
    #pragma unroll
    for (int k = 0; k < 11; ++k) {
        int tt = t0 - 3 + k;
        xv[k] = (tt >= 0) ? b2f(xz[(size_t)(r0 - 3 + k) * 1024 + d]) : 0.f;
    }
    #pragma unroll
    for (int j = 0; j < 8; ++j) {
        float acc = bs;
        acc = fmaf(w0, xv[j + 0], acc);
        acc = fmaf(w1, xv[j + 1], acc);
        acc = fmaf(w2, xv[j + 2], acc);
        acc = fmaf(w3, xv[j + 3], acc);
        xi[(size_t)(r0 + j) * 512 + d] = f2b(siluf(acc));
    }
}

// ---------------------------------------------------------------------------
// Chunked scan.  Thread owns channel d (16 states in regs); dt precomputed.
// bid = ((db*NCHUNK + chunk)*2 + half); d = half*256 + tid.
// Fast path: a[n] == (n+1)*a[0]  =>  dA_n = q^(n+1), q = exp(dt*a0).
// ---------------------------------------------------------------------------
__device__ __forceinline__ void scan_head(int bid, int tid,
    int& db, int& b, int& dir, int& chunk, int& d, size_t& row0)
{
    int half = bid & 1;
    int tmp = bid >> 1;
    chunk = tmp & (NCHUNK - 1);
    db = tmp >> 7;
    b = db & 1; dir = db >> 1;
    d = half * 256 + tid;
    row0 = (size_t)b * T_SEQ + (size_t)chunk * CLEN;
}

__device__ __forceinline__ void load_a16(const float* __restrict__ Al, int d,
                                         float* a, bool& fast)
{
    const float4* ap = reinterpret_cast<const float4*>(Al + (size_t)d * 16);
    #pragma unroll
    for (int i = 0; i < 4; ++i) {
        float4 v = ap[i];
        a[4*i+0] = -expf(v.x); a[4*i+1] = -expf(v.y);
        a[4*i+2] = -expf(v.z); a[4*i+3] = -expf(v.w);
    }
    fast = true;
    #pragma unroll
    for (int n = 1; n < 16; ++n)
        fast = fast && (fabsf(a[n] - (float)(n + 1) * a[0]) <= 1e-4f * (float)(n + 1));
}

#define LD16(dst, src_t)                                              \
    {                                                                 \
        const float4* q_ = reinterpret_cast<const float4*>(src_t);    \
        float4 q0 = q_[0], q1 = q_[1], q2 = q_[2], q3 = q_[3];        \
        dst[0]=q0.x; dst[1]=q0.y; dst[2]=q0.z; dst[3]=q0.w;           \
        dst[4]=q1.x; dst[5]=q1.y; dst[6]=q1.z; dst[7]=q1.w;           \
        dst[8]=q2.x; dst[9]=q2.y; dst[10]=q2.z; dst[11]=q2.w;         \
        dst[12]=q3.x; dst[13]=q3.y; dst[14]=q3.z; dst[15]=q3.w;       \
    }

__global__ __launch_bounds__(256)
void scan_pass1(const ushort* __restrict__ xi_f, const ushort* __restrict__ xi_b,
                const float* __restrict__ dt_f, const float* __restrict__ dt_b,
                const float* __restrict__ xd_f, const float* __restrict__ xd_b,
                const float* __restrict__ Al_f, const float* __restrict__ Al_b,
                float* __restrict__ Acum, float* __restrict__ Hloc)
{
    __shared__ float Bsh[CLEN][16];
    int db, b, dir, chunk, d; size_t row0;
    scan_head(blockIdx.x, threadIdx.x, db, b, dir, chunk, d, row0);

    const ushort* xi = dir ? xi_b : xi_f;
    const float* dt  = dir ? dt_b : dt_f;
    const float* xd  = dir ? xd_b : xd_f;
    const float* Al  = dir ? Al_b : Al_f;

    float a[16]; bool fast;
    load_a16(Al, d, a, fast);

    for (int i = threadIdx.x; i < CLEN * 16; i += 256) {
        int r = i >> 4, n = i & 15;
        Bsh[r][n] = xd[(row0 + r) * 32 + n];
    }
    __syncthreads();

    const ushort* xip = xi + row0 * 512 + d;
    const float*  dtp = dt + row0 * 512 + d;
    float h[16] = {};
    float sumdt = 0.f;

    if (fast) {
        #pragma unroll 2
        for (int t = 0; t < CLEN; ++t) {
            float bn[16]; LD16(bn, Bsh[t]);
            float dtv = dtp[(size_t)t * 512];
            float xiv = b2f(xip[(size_t)t * 512]);
            float dbx = dtv * xiv;
            sumdt += dtv;
            float qv = __expf(dtv * a[0]);
            float dA = qv;
            #pragma unroll
            for (int n = 0; n < 16; ++n) {
                h[n] = fmaf(dA, h[n], dbx * bn[n]);
                dA *= qv;
            }
        }
    } else {
        #pragma unroll 2
        for (int t = 0; t < CLEN; ++t) {
            float bn[16]; LD16(bn, Bsh[t]);
            float dtv = dtp[(size_t)t * 512];
            float xiv = b2f(xip[(size_t)t * 512]);
            float dbx = dtv * xiv;
            sumdt += dtv;
            #pragma unroll
            for (int n = 0; n < 16; ++n) {
                float dA = __expf(dtv * a[n]);
                h[n] = fmaf(dA, h[n], dbx * bn[n]);
            }
        }
    }

    size_t si = ((size_t)((db * NCHUNK + chunk) * 512 + d)) * 16;
    float4* Ao = reinterpret_cast<float4*>(Acum + si);
    float4* Ho = reinterpret_cast<float4*>(Hloc + si);
    #pragma unroll
    for (int i = 0; i < 4; ++i) {
        Ao[i] = make_float4(__expf(a[4*i+0]*sumdt), __expf(a[4*i+1]*sumdt),
                            __expf(a[4*i+2]*sumdt), __expf(a[4*i+3]*sumdt));
        Ho[i] = make_float4(h[4*i+0], h[4*i+1], h[4*i+2], h[4*i+3]);
    }
}

__global__ __launch_bounds__(256)
void scan_pass2(const float* __restrict__ Acum, const float* __restrict__ Hloc,
                float* __restrict__ Hin)
{
    int tid = blockIdx.x * 256 + threadIdx.x;
    int db = tid >> 13;
    int dn = tid & 8191;
    size_t base = (size_t)db * NCHUNK * 8192 + dn;
    float h = 0.f;
    #pragma unroll 8
    for (int c = 0; c < NCHUNK; ++c) {
        size_t si = base + (size_t)c * 8192;
        Hin[si] = h;
        h = fmaf(Acum[si], h, Hloc[si]);
    }
}

// pass3: replay from h_in, fused gate.  Writes single y_all[ROWS][1024]:
//   dir 0 -> cols 0..511 at natural rows
//   dir 1 -> cols 512..1023 at UNFLIPPED rows (so G5 needs no flip; K-concat)
__global__ __launch_bounds__(256)
void scan_pass3(const ushort* __restrict__ xi_f, const ushort* __restrict__ xi_b,
                const float* __restrict__ dt_f, const float* __restrict__ dt_b,
                const float* __restrict__ xd_f, const float* __restrict__ xd_b,
                const float* __restrict__ Al_f, const float* __restrict__ Al_b,
                const ushort* __restrict__ xz_f, const ushort* __restrict__ xz_b,
                const float* __restrict__ D_f, const float* __restrict__ D_b,
                const float* __restrict__ Hin,
                ushort* __restrict__ y_all)
{
    __shared__ float Bsh[CLEN][16];
    __shared__ float Csh[CLEN][16];
    int db, b, dir, chunk, d; size_t row0;
    scan_head(blockIdx.x, threadIdx.x, db, b, dir, chunk, d, row0);

    const ushort* xi = dir ? xi_b : xi_f;
    const float* dt  = dir ? dt_b : dt_f;
    const float* xd  = dir ? xd_b : xd_f;
    const float* Al  = dir ? Al_b : Al_f;
    const ushort* xz = dir ? xz_b : xz_f;
    const float* Dv  = dir ? D_b  : D_f;

    float a[16]; bool fast;
    load_a16(Al, d, a, fast);
    float Dd = Dv[d];

    for (int i = threadIdx.x; i < CLEN * 32; i += 256) {
        int r = i >> 5, c = i & 31;
        float v = xd[(row0 + r) * 32 + c];
        if (c < 16) Bsh[r][c] = v; else Csh[r][c - 16] = v;
    }
    __syncthreads();

    float h[16];
    {
        size_t si = ((size_t)((db * NCHUNK + chunk) * 512 + d)) * 16;
        const float4* hp = reinterpret_cast<const float4*>(Hin + si);
        #pragma unroll
        for (int i = 0; i < 4; ++i) {
            float4 v = hp[i];
            h[4*i+0] = v.x; h[4*i+1] = v.y; h[4*i+2] = v.z; h[4*i+3] = v.w;
        }
    }

    const ushort* xip = xi + row0 * 512 + d;
    const float*  dtp = dt + row0 * 512 + d;
    const ushort* zp  = xz + row0 * 1024 + 512 + d;

    // y write pointer (unflipped rows for bw)
    ushort* yp;
    long ystep;
    if (dir == 0) {
        yp = y_all + row0 * 1024 + d;
        ystep = 1024;
    } else {
        size_t rowu = (size_t)b * T_SEQ + (T_SEQ - 1) - (size_t)chunk * CLEN;
        yp = y_all + rowu * 1024 + 512 + d;
        ystep = -1024;
    }

    if (fast) {
        #pragma unroll 2
        for (int t = 0; t < CLEN; ++t) {
            float bn[16]; LD16(bn, Bsh[t]);
            float cn[16]; LD16(cn, Csh[t]);
            float dtv = dtp[(size_t)t * 512];
            float xiv = b2f(xip[(size_t)t * 512]);
            float zv  = b2f(zp[(size_t)t * 1024]);
            float dbx = dtv * xiv;
            float qv = __expf(dtv * a[0]);
            float dA = qv;
            float yacc = 0.f;
            #pragma unroll
            for (int n = 0; n < 16; ++n) {
                h[n] = fmaf(dA, h[n], dbx * bn[n]);
                yacc = fmaf(h[n], cn[n], yacc);
                dA *= qv;
            }
            yp[(long)t * ystep] = f2b(fmaf(xiv, Dd, yacc) * siluf(zv));
        }
    } else {
        #pragma unroll 2
        for (int t = 0; t < CLEN; ++t) {
            float bn[16]; LD16(bn, Bsh[t]);
            float cn[16]; LD16(cn, Csh[t]);
            float dtv = dtp[(size_t)t * 512];
            float xiv = b2f(xip[(size_t)t * 512]);
            float zv  = b2f(zp[(size_t)t * 1024]);
            float dbx = dtv * xiv;
            float yacc = 0.f;
            #pragma unroll
            for (int n = 0; n < 16; ++n) {
                float dA = __expf(dtv * a[n]);
                h[n] = fmaf(dA, h[n], dbx * bn[n]);
                yacc = fmaf(h[n], cn[n], yacc);
            }
            yp[(long)t * ystep] = f2b(fmaf(xiv, Dd, yacc) * siluf(zv));
        }
    }
}

// ---------------------------------------------------------------------------
extern "C" void kernel_launch(void* const* d_in, const int* in_sizes, int n_in,
                              void* d_out, int out_size, void* d_ws, size_t ws_size,
                              hipStream_t stream)
{
    const float* x       = (const float*)d_in[0];
    const float* fW_in   = (const float*)d_in[1];
    const float* fconv_w = (const float*)d_in[2];
    const float* fconv_b = (const float*)d_in[3];
    const float* fW_x    = (const float*)d_in[4];
    const float* fW_dt   = (const float*)d_in[5];
    const float* fb_dt   = (const float*)d_in[6];
    const float* fA_log  = (const float*)d_in[7];
    const float* fD      = (const float*)d_in[8];
    const float* fW_out  = (const float*)d_in[9];
    const float* bW_in   = (const float*)d_in[10];
    const float* bconv_w = (const float*)d_in[11];
    const float* bconv_b = (const float*)d_in[12];
    const float* bW_x    = (const float*)d_in[13];
    const float* bW_dt   = (const float*)d_in[14];
    const float* bb_dt   = (const float*)d_in[15];
    const float* bA_log  = (const float*)d_in[16];
    const float* bD      = (const float*)d_in[17];
    const float* bW_out  = (const float*)d_in[18];
    const float* merge   = (const float*)d_in[19];
    float* out = (float*)d_out;

    char* ws = (char*)d_ws;
    ushort* xbh     = (ushort*)ws; ws += (size_t)ROWS * 256 * 2;
    ushort* WinT_f  = (ushort*)ws; ws += (size_t)1024 * 256 * 2;
    ushort* WinT_b  = (ushort*)ws; ws += (size_t)1024 * 256 * 2;
    ushort* WallOut = (ushort*)ws; ws += (size_t)256 * 1024 * 2;   // G5 weights [256][1024]
    ushort* Wall_f  = (ushort*)ws; ws += (size_t)640 * 512 * 2;
    ushort* Wall_b  = (ushort*)ws; ws += (size_t)640 * 512 * 2;
    ushort* xz_f    = (ushort*)ws; ws += (size_t)ROWS * 1024 * 2;
    ushort* xz_b    = (ushort*)ws; ws += (size_t)ROWS * 1024 * 2;
    ushort* xi_f    = (ushort*)ws; ws += (size_t)ROWS * 512 * 2;
    ushort* xi_b    = (ushort*)ws; ws += (size_t)ROWS * 512 * 2;
    ushort* y_all   = (ushort*)ws; ws += (size_t)ROWS * 1024 * 2;
    float*  dt_f    = (float*)ws;  ws += (size_t)ROWS * 512 * 4;
    float*  dt_b    = (float*)ws;  ws += (size_t)ROWS * 512 * 4;
    float*  xd_f    = (float*)ws;  ws += (size_t)ROWS * 32 * 4;
    float*  xd_b    = (float*)ws;  ws += (size_t)ROWS * 32 * 4;
    float*  Acum    = (float*)ws;  ws += (size_t)4 * NCHUNK * 8192 * 4;
    float*  Hloc    = (float*)ws;  ws += (size_t)4 * NCHUNK * 8192 * 4;
    float*  Hin     = (float*)ws;  ws += (size_t)4 * NCHUNK * 8192 * 4;

    dim3 blk(256);

    // prep
    cvt_bf16<<<1024, blk, 0, stream>>>(x, xbh);
    transpose_w<<<128, blk, 0, stream>>>(fW_in, WinT_f, 256, 1024);
    transpose_w<<<128, blk, 0, stream>>>(bW_in, WinT_b, 256, 1024);
    fusewT<<<512, blk, 0, stream>>>(fW_out, merge, WallOut, 0, 0);
    fusewT<<<512, blk, 0, stream>>>(bW_out, merge, WallOut, 256, 512);
    wallT<<<160, blk, 0, stream>>>(fW_x, fW_dt, Wall_f);
    wallT<<<160, blk, 0, stream>>>(bW_x, bW_dt, Wall_b);

    // G1: xz = x @ W_in, both dirs (z picks dir; bw flips rows)  K=256
    mgemm<64, 128, 1><<<dim3(8, 128, 2), blk, 0, stream>>>(
        xbh, xbh, WinT_f, WinT_b, xz_f, xz_b, nullptr, nullptr, nullptr, nullptr,
        256, 1024, 0, 1, 1, 1);

    // conv + silu (both dirs)
    conv_kernel<<<4096, blk, 0, stream>>>(xz_f, xz_b, fconv_w, bconv_w,
                                          fconv_b, bconv_b, xi_f, xi_b);

    // dt+xd merged: [dt | xd | pad] = xi @ Wall^T (640 cols = 5x128 tiles)
    mgemm<64, 128, 2><<<dim3(5, 128, 2), blk, 0, stream>>>(
        xi_f, xi_b, Wall_f, Wall_b, dt_f, dt_b, fb_dt, bb_dt, xd_f, xd_b,
        512, 512, 0, 0, 1, 1);

    // chunked scan
    scan_pass1<<<1024, blk, 0, stream>>>(xi_f, xi_b, dt_f, dt_b, xd_f, xd_b,
                                         fA_log, bA_log, Acum, Hloc);
    scan_pass2<<<128, blk, 0, stream>>>(Acum, Hloc, Hin);
    scan_pass3<<<1024, blk, 0, stream>>>(xi_f, xi_b, dt_f, dt_b, xd_f, xd_b,
                                         fA_log, bA_log, xz_f, xz_b, fD, bD,
                                         Hin, y_all);

    // G5: out = y_all @ WallOut^T  (single un-flipped GEMM, K=1024)
    mgemm<64, 64, 0><<<dim3(4, 128, 1), blk, 0, stream>>>(
        y_all, nullptr, WallOut, nullptr, out, nullptr, nullptr, nullptr,
        nullptr, nullptr, 1024, 256, 0, 0, 0, 1);
}

// Round 10
// 173.127 us; speedup vs baseline: 1.7484x; 1.1585x over previous
//
#include <hip/hip_runtime.h>
#include <math.h>

#define T_SEQ 4096
#define ROWS 8192
#define NCHUNK 128
#define CLEN 32

typedef __attribute__((ext_vector_type(4))) float f32x4;
typedef __attribute__((ext_vector_type(2))) float f32x2;
typedef __attribute__((ext_vector_type(8))) short s16x8;

#if __has_builtin(__builtin_elementwise_fma)
#define PKFMA(a, b, c) __builtin_elementwise_fma((a), (b), (c))
#else
#define PKFMA(a, b, c) ((a) * (b) + (c))
#endif

__device__ __forceinline__ float siluf(float x) { return x / (1.f + __expf(-x)); }
__device__ __forceinline__ float softplusf(float x) {
    return fmaxf(x, 0.f) + __logf(1.f + __expf(-fabsf(x)));
}
__device__ __forceinline__ ushort f2b(float f) {
    uint u = __float_as_uint(f);
    u += 0x7fffu + ((u >> 16) & 1u);
    return (ushort)(u >> 16);
}
__device__ __forceinline__ float b2f(ushort h) { return __uint_as_float(((uint)h) << 16); }

// direct global->LDS, 16B per lane.
__device__ __forceinline__ void gl16(const ushort* g, const char* l)
{
    __builtin_amdgcn_global_load_lds(
        (const __attribute__((address_space(1))) void*)g,
        (__attribute__((address_space(3))) void*)l,
        16, 0, 0);
}

// ---------------------------------------------------------------------------
// Merged prep kernel (one launch instead of 7):
//  blocks 0..1023    : x fp32 -> bf16 (xbh)
//  1024..1151        : transpose fW_in -> WinT_f [1024][256]
//  1152..1279        : transpose bW_in -> WinT_b
//  1280..1791        : fusewT fw -> WallOut[:, 0:512)   (koff=0,   mrow0=0)
//  1792..2303        : fusewT bw -> WallOut[:, 512:1024) (koff=512, mrow0=256)
//  2304..2463        : wallT fw -> Wall_f [640][512]
//  2464..2623        : wallT bw -> Wall_b
// ---------------------------------------------------------------------------
__device__ __forceinline__ void cvt_body(const float* in, ushort* out, int bid, int tid)
{
    int i = bid * 256 + tid;
    const float4* p = reinterpret_cast<const float4*>(in) + (size_t)i * 2;
    float4 a = p[0], b = p[1];
    s16x8 v;
    v[0] = (short)f2b(a.x); v[1] = (short)f2b(a.y); v[2] = (short)f2b(a.z); v[3] = (short)f2b(a.w);
    v[4] = (short)f2b(b.x); v[5] = (short)f2b(b.y); v[6] = (short)f2b(b.z); v[7] = (short)f2b(b.w);
    *reinterpret_cast<s16x8*>(out + (size_t)i * 8) = v;
}

__device__ __forceinline__ void transpose_body(const float* W, ushort* WT,
                                               int Kdim, int Ndim, int bid, int tid)
{
    int idx = bid * 256 + tid;
    int kg8 = Kdim >> 3;
    if (idx >= Ndim * kg8) return;
    int n = idx / kg8, kg = idx - n * kg8;
    s16x8 v;
    #pragma unroll
    for (int i = 0; i < 8; ++i)
        v[i] = (short)f2b(W[(size_t)(kg * 8 + i) * Ndim + n]);
    *reinterpret_cast<s16x8*>(WT + (size_t)n * Kdim + kg * 8) = v;
}

__device__ __forceinline__ void fusew_body(const float* W_out, const float* merge,
                                           ushort* WT, int mrow0, int koff, int bid, int tid)
{
    int idx = bid * 256 + tid;   // dd*256 + j
    int dd = idx >> 8, j = idx & 255;
    float acc = 0.f;
    const float* wr = W_out + dd * 256;
    const float* mc = merge + (size_t)mrow0 * 256 + j;
    #pragma unroll 4
    for (int m = 0; m < 256; ++m)
        acc = fmaf(wr[m], mc[(size_t)m * 256], acc);
    WT[(size_t)j * 1024 + koff + dd] = f2b(acc);
}

__device__ __forceinline__ void wall_body(const float* Wx, const float* Wdt,
                                          ushort* WT, int bid, int tid)
{
    int idx = bid * 256 + tid;   // n*64 + kg
    int n = idx >> 6, kg = idx & 63;
    s16x8 v;
    #pragma unroll
    for (int i = 0; i < 8; ++i) {
        int k = kg * 8 + i;
        float acc = 0.f;
        if (n < 512) {
            #pragma unroll
            for (int j = 0; j < 16; ++j)
                acc = fmaf(Wx[k * 48 + j], Wdt[j * 512 + n], acc);
        } else if (n < 544) {
            acc = Wx[k * 48 + 16 + (n - 512)];
        }
        v[i] = (short)f2b(acc);
    }
    *reinterpret_cast<s16x8*>(WT + (size_t)n * 512 + kg * 8) = v;
}

__global__ __launch_bounds__(256)
void prep_kernel(const float* __restrict__ x,
                 const float* __restrict__ fW_in, const float* __restrict__ bW_in,
                 const float* __restrict__ fW_out, const float* __restrict__ bW_out,
                 const float* __restrict__ merge,
                 const float* __restrict__ fW_x, const float* __restrict__ fW_dt,
                 const float* __restrict__ bW_x, const float* __restrict__ bW_dt,
                 ushort* __restrict__ xbh,
                 ushort* __restrict__ WinT_f, ushort* __restrict__ WinT_b,
                 ushort* __restrict__ WallOut,
                 ushort* __restrict__ Wall_f, ushort* __restrict__ Wall_b)
{
    int bid = blockIdx.x, tid = threadIdx.x;
    if (bid < 1024)        cvt_body(x, xbh, bid, tid);
    else if (bid < 1152)   transpose_body(fW_in, WinT_f, 256, 1024, bid - 1024, tid);
    else if (bid < 1280)   transpose_body(bW_in, WinT_b, 256, 1024, bid - 1152, tid);
    else if (bid < 1792)   fusew_body(fW_out, merge, WallOut, 0, 0, bid - 1280, tid);
    else if (bid < 2304)   fusew_body(bW_out, merge, WallOut, 256, 512, bid - 1792, tid);
    else if (bid < 2464)   wall_body(fW_x, fW_dt, Wall_f, bid - 2304, tid);
    else                   wall_body(bW_x, bW_dt, Wall_b, bid - 2464, tid);
}

// ---------------------------------------------------------------------------
// bf16 MFMA GEMM, m97 structure (unchanged from R9).
// ---------------------------------------------------------------------------
template<int BM, int BN, int EPI>
__global__ __launch_bounds__(256)
void mgemm(const ushort* __restrict__ A0, const ushort* __restrict__ A1,
           const ushort* __restrict__ B0, const ushort* __restrict__ B1,
           void* __restrict__ C0, void* __restrict__ C1,
           const float* __restrict__ bias0, const float* __restrict__ bias1,
           float* __restrict__ X0, float* __restrict__ X1,
           int K, int ldc, int flip0, int flip1, int zmode, int nseg)
{
    constexpr int MF = BM / 32, NF = BN / 32;
    constexpr int ASTR = BM / 32, BSTR = BN / 32;
    constexpr int ABYTES = BM * 128;
    __shared__ char lds[BM * 128 + BN * 128];

    const int tid = threadIdx.x;
    const int L = tid & 63, w = tid >> 6;
    const int wm = w >> 1, wn = w & 1;
    const int m0 = blockIdx.y * BM, n0 = blockIdx.x * BN;

    f32x4 acc[MF][NF];
    #pragma unroll
    for (int i = 0; i < MF; ++i)
        #pragma unroll
        for (int j = 0; j < NF; ++j)
            acc[i][j] = (f32x4){0.f, 0.f, 0.f, 0.f};

    const int rsub = L >> 3;
    const int q = (L & 7) ^ rsub;
    const int sb = zmode ? blockIdx.z : 0;
    const int se = zmode ? sb + 1 : nseg;

    for (int s = sb; s < se; ++s) {
        const ushort* Ap = s ? A1 : A0;
        const ushort* Bp = s ? B1 : B0;
        const int flip = s ? flip1 : flip0;

        const ushort* ap[ASTR];
        const ushort* bp[BSTR];
        #pragma unroll
        for (int c = 0; c < ASTR; ++c) {
            int rg = m0 + (w * ASTR + c) * 8 + rsub;
            if (flip) rg ^= (T_SEQ - 1);
            ap[c] = Ap + (size_t)rg * K + q * 8;
        }
        #pragma unroll
        for (int c = 0; c < BSTR; ++c) {
            int ng = n0 + (w * BSTR + c) * 8 + rsub;
            bp[c] = Bp + (size_t)ng * K + q * 8;
        }

        for (int k0 = 0; k0 < K; k0 += 64) {
            #pragma unroll
            for (int c = 0; c < ASTR; ++c) {
                gl16(ap[c], lds + (w * ASTR + c) * 1024);
                ap[c] += 64;
            }
            #pragma unroll
            for (int c = 0; c < BSTR; ++c) {
                gl16(bp[c], lds + ABYTES + (w * BSTR + c) * 1024);
                bp[c] += 64;
            }
            __syncthreads();
            #pragma unroll
            for (int kk = 0; kk < 2; ++kk) {
                const int sw = (((kk * 4 + (L >> 4)) ^ (L & 7)) << 4);
                s16x8 af[MF], bf[NF];
                #pragma unroll
                for (int i = 0; i < MF; ++i) {
                    int R = wm * (BM / 2) + i * 16 + (L & 15);
                    af[i] = *reinterpret_cast<const s16x8*>(lds + R * 128 + sw);
                }
                #pragma unroll
                for (int j = 0; j < NF; ++j) {
                    int R = wn * (BN / 2) + j * 16 + (L & 15);
                    bf[j] = *reinterpret_cast<const s16x8*>(lds + ABYTES + R * 128 + sw);
                }
                #pragma unroll
                for (int i = 0; i < MF; ++i)
                    #pragma unroll
                    for (int j = 0; j < NF; ++j)
                        acc[i][j] = __builtin_amdgcn_mfma_f32_16x16x32_bf16(
                            af[i], bf[j], acc[i][j], 0, 0, 0);
            }
            __syncthreads();
        }
    }

    void* Cv = (zmode && blockIdx.z) ? C1 : C0;
    const float* bias = (zmode && blockIdx.z) ? bias1 : bias0;
    float* Xv = (zmode && blockIdx.z) ? X1 : X0;
    #pragma unroll
    for (int i = 0; i < MF; ++i) {
        #pragma unroll
        for (int j = 0; j < NF; ++j) {
            int r0 = m0 + wm * (BM / 2) + i * 16 + ((L >> 4) << 2);
            int c  = n0 + wn * (BN / 2) + j * 16 + (L & 15);
            if (EPI == 2) {
                if (c < 512) {
                    float bv = bias[c];
                    #pragma unroll
                    for (int r = 0; r < 4; ++r)
                        ((float*)Cv)[(size_t)(r0 + r) * 512 + c] =
                            softplusf(acc[i][j][r] + bv);
                } else if (c < 544) {
                    #pragma unroll
                    for (int r = 0; r < 4; ++r)
                        Xv[(size_t)(r0 + r) * 32 + (c - 512)] = acc[i][j][r];
                }
            } else {
                #pragma unroll
                for (int r = 0; r < 4; ++r) {
                    size_t o = (size_t)(r0 + r) * ldc + c;
                    if (EPI == 1) ((ushort*)Cv)[o] = f2b(acc[i][j][r]);
                    else          ((float*)Cv)[o]  = acc[i][j][r];
                }
            }
        }
    }
}

// ---------------------------------------------------------------------------
// Causal depthwise conv (4 taps) + bias + silu, bf16 in/out, 8 rows/thread.
// ---------------------------------------------------------------------------
__global__ __launch_bounds__(256)
void conv_kernel(const ushort* __restrict__ xz_f, const ushort* __restrict__ xz_b,
                 const float* __restrict__ w_f, const float* __restrict__ w_b,
                 const float* __restrict__ bias_f, const float* __restrict__ bias_b,
                 ushort* __restrict__ xi_f, ushort* __restrict__ xi_b)
{
    int gid = blockIdx.x;
    int dir = gid >> 11;
    const ushort* xz  = dir ? xz_b : xz_f;
    const float*  w   = dir ? w_b : w_f;
    const float*  bia = dir ? bias_b : bias_f;
    ushort*       xi  = dir ? xi_b : xi_f;

    int idx = (gid & 2047) * 256 + threadIdx.x;   // rb*512 + d
    int rb = idx >> 9, d = idx & 511;
    int r0 = rb * 8;
    int t0 = r0 & (T_SEQ - 1);
    float w0 = w[d * 4 + 0], w1 = w[d * 4 + 1], w2 = w[d * 4 + 2], w3 = w[d * 4 + 3];
    float bs = bia[d];

    float xv[11];
    #pragma unroll
    for (int k = 0; k < 11; ++k) {
        int tt = t0 - 3 + k;
        xv[k] = (tt >= 0) ? b2f(xz[(size_t)(r0 - 3 + k) * 1024 + d]) : 0.f;
    }
    #pragma unroll
    for (int j = 0; j < 8; ++j) {
        float acc = bs;
        acc = fmaf(w0, xv[j + 0], acc);
        acc = fmaf(w1, xv[j + 1], acc);
        acc = fmaf(w2, xv[j + 2], acc);
        acc = fmaf(w3, xv[j + 3], acc);
        xi[(size_t)(r0 + j) * 512 + d] = f2b(siluf(acc));
    }
}

// ---------------------------------------------------------------------------
// Chunked scan, packed-fp32 inner loops (v_pk_fma_f32 via float2 vectors).
// Thread owns channel d (16 states as 8 x f32x2); dt precomputed.
// Fast path: a[n] == (n+1)*a[0]  =>  dA pairs {q^(2j+1), q^(2j+2)}.
// ---------------------------------------------------------------------------
__device__ __forceinline__ void scan_head(int bid, int tid,
    int& db, int& b, int& dir, int& chunk, int& d, size_t& row0)
{
    int half = bid & 1;
    int tmp = bid >> 1;
    chunk = tmp & (NCHUNK - 1);
    db = tmp >> 7;
    b = db & 1; dir = db >> 1;
    d = half * 256 + tid;
    row0 = (size_t)b * T_SEQ + (size_t)chunk * CLEN;
}

__device__ __forceinline__ void load_a16(const float* __restrict__ Al, int d,
                                         float* a, bool& fast)
{
    const float4* ap = reinterpret_cast<const float4*>(Al + (size_t)d * 16);
    #pragma unroll
    for (int i = 0; i < 4; ++i) {
        float4 v = ap[i];
        a[4*i+0] = -expf(v.x); a[4*i+1] = -expf(v.y);
        a[4*i+2] = -expf(v.z); a[4*i+3] = -expf(v.w);
    }
    fast = true;
    #pragma unroll
    for (int n = 1; n < 16; ++n)
        fast = fast && (fabsf(a[n] - (float)(n + 1) * a[0]) <= 1e-4f * (float)(n + 1));
}

#define LD16(dst, src_t)                                              \
    {                                                                 \
        const float4* q_ = reinterpret_cast<const float4*>(src_t);    \
        float4 q0 = q_[0], q1 = q_[1], q2 = q_[2], q3 = q_[3];        \
        dst[0]=q0.x; dst[1]=q0.y; dst[2]=q0.z; dst[3]=q0.w;           \
        dst[4]=q1.x; dst[5]=q1.y; dst[6]=q1.z; dst[7]=q1.w;           \
        dst[8]=q2.x; dst[9]=q2.y; dst[10]=q2.z; dst[11]=q2.w;         \
        dst[12]=q3.x; dst[13]=q3.y; dst[14]=q3.z; dst[15]=q3.w;       \
    }

__global__ __launch_bounds__(256)
void scan_pass1(const ushort* __restrict__ xi_f, const ushort* __restrict__ xi_b,
                const float* __restrict__ dt_f, const float* __restrict__ dt_b,
                const float* __restrict__ xd_f, const float* __restrict__ xd_b,
                const float* __restrict__ Al_f, const float* __restrict__ Al_b,
                float* __restrict__ Acum, float* __restrict__ Hloc)
{
    __shared__ float Bsh[CLEN][16];
    int db, b, dir, chunk, d; size_t row0;
    scan_head(blockIdx.x, threadIdx.x, db, b, dir, chunk, d, row0);

    const ushort* xi = dir ? xi_b : xi_f;
    const float* dt  = dir ? dt_b : dt_f;
    const float* xd  = dir ? xd_b : xd_f;
    const float* Al  = dir ? Al_b : Al_f;

    float a[16]; bool fast;
    load_a16(Al, d, a, fast);

    for (int i = threadIdx.x; i < CLEN * 16; i += 256) {
        int r = i >> 4, n = i & 15;
        Bsh[r][n] = xd[(row0 + r) * 32 + n];
    }
    __syncthreads();

    const ushort* xip = xi + row0 * 512 + d;
    const float*  dtp = dt + row0 * 512 + d;
    float h[16];
    float sumdt = 0.f;

    if (fast) {
        f32x2 h2[8];
        #pragma unroll
        for (int j = 0; j < 8; ++j) h2[j] = (f32x2){0.f, 0.f};
        for (int t = 0; t < CLEN; ++t) {
            float dtv = dtp[(size_t)t * 512];
            float xiv = b2f(xip[(size_t)t * 512]);
            float dbx = dtv * xiv;
            sumdt += dtv;
            float qv = __expf(dtv * a[0]);
            float q2 = qv * qv;
            f32x2 Q2 = (f32x2){q2, q2};
            f32x2 p  = (f32x2){qv, q2};
            f32x2 dbx2 = (f32x2){dbx, dbx};
            const f32x2* bq = reinterpret_cast<const f32x2*>(Bsh[t]);
            #pragma unroll
            for (int j = 0; j < 8; ++j) {
                f32x2 r = bq[j] * dbx2;
                h2[j] = PKFMA(p, h2[j], r);
                if (j < 7) p = p * Q2;
            }
        }
        #pragma unroll
        for (int j = 0; j < 8; ++j) { h[2*j] = h2[j][0]; h[2*j+1] = h2[j][1]; }
    } else {
        #pragma unroll
        for (int n = 0; n < 16; ++n) h[n] = 0.f;
        for (int t = 0; t < CLEN; ++t) {
            float bn[16]; LD16(bn, Bsh[t]);
            float dtv = dtp[(size_t)t * 512];
            float xiv = b2f(xip[(size_t)t * 512]);
            float dbx = dtv * xiv;
            sumdt += dtv;
            #pragma unroll
            for (int n = 0; n < 16; ++n) {
                float dA = __expf(dtv * a[n]);
                h[n] = fmaf(dA, h[n], dbx * bn[n]);
            }
        }
    }

    size_t si = ((size_t)((db * NCHUNK + chunk) * 512 + d)) * 16;
    float4* Ao = reinterpret_cast<float4*>(Acum + si);
    float4* Ho = reinterpret_cast<float4*>(Hloc + si);
    #pragma unroll
    for (int i = 0; i < 4; ++i) {
        Ao[i] = make_float4(__expf(a[4*i+0]*sumdt), __expf(a[4*i+1]*sumdt),
                            __expf(a[4*i+2]*sumdt), __expf(a[4*i+3]*sumdt));
        Ho[i] = make_float4(h[4*i+0], h[4*i+1], h[4*i+2], h[4*i+3]);
    }
}

__global__ __launch_bounds__(256)
void scan_pass2(const float* __restrict__ Acum, const float* __restrict__ Hloc,
                float* __restrict__ Hin)
{
    int tid = blockIdx.x * 256 + threadIdx.x;
    int db = tid >> 13;
    int dn = tid & 8191;
    size_t base = (size_t)db * NCHUNK * 8192 + dn;
    float h = 0.f;
    #pragma unroll 8
    for (int c = 0; c < NCHUNK; ++c) {
        size_t si = base + (size_t)c * 8192;
        Hin[si] = h;
        h = fmaf(Acum[si], h, Hloc[si]);
    }
}

// pass3: replay from h_in, fused gate.  Writes single y_all[ROWS][1024]:
//   dir 0 -> cols 0..511 at natural rows
//   dir 1 -> cols 512..1023 at UNFLIPPED rows (so G5 needs no flip; K-concat)
__global__ __launch_bounds__(256)
void scan_pass3(const ushort* __restrict__ xi_f, const ushort* __restrict__ xi_b,
                const float* __restrict__ dt_f, const float* __restrict__ dt_b,
                const float* __restrict__ xd_f, const float* __restrict__ xd_b,
                const float* __restrict__ Al_f, const float* __restrict__ Al_b,
                const ushort* __restrict__ xz_f, const ushort* __restrict__ xz_b,
                const float* __restrict__ D_f, const float* __restrict__ D_b,
                const float* __restrict__ Hin,
                ushort* __restrict__ y_all)
{
    __shared__ float Bsh[CLEN][16];
    __shared__ float Csh[CLEN][16];
    int db, b, dir, chunk, d; size_t row0;
    scan_head(blockIdx.x, threadIdx.x, db, b, dir, chunk, d, row0);

    const ushort* xi = dir ? xi_b : xi_f;
    const float* dt  = dir ? dt_b : dt_f;
    const float* xd  = dir ? xd_b : xd_f;
    const float* Al  = dir ? Al_b : Al_f;
    const ushort* xz = dir ? xz_b : xz_f;
    const float* Dv  = dir ? D_b  : D_f;

    float a[16]; bool fast;
    load_a16(Al, d, a, fast);
    float Dd = Dv[d];

    for (int i = threadIdx.x; i < CLEN * 32; i += 256) {
        int r = i >> 5, c = i & 31;
        float v = xd[(row0 + r) * 32 + c];
        if (c < 16) Bsh[r][c] = v; else Csh[r][c - 16] = v;
    }
    __syncthreads();

    const ushort* xip = xi + row0 * 512 + d;
    const float*  dtp = dt + row0 * 512 + d;
    const ushort* zp  = xz + row0 * 1024 + 512 + d;

    // y write pointer (unflipped rows for bw)
    ushort* yp;
    long ystep;
    if (dir == 0) {
        yp = y_all + row0 * 1024 + d;
        ystep = 1024;
    } else {
        size_t rowu = (size_t)b * T_SEQ + (T_SEQ - 1) - (size_t)chunk * CLEN;
        yp = y_all + rowu * 1024 + 512 + d;
        ystep = -1024;
    }

    size_t si = ((size_t)((db * NCHUNK + chunk) * 512 + d)) * 16;

    if (fast) {
        f32x2 h2[8];
        {
            const f32x2* hp = reinterpret_cast<const f32x2*>(Hin + si);
            #pragma unroll
            for (int j = 0; j < 8; ++j) h2[j] = hp[j];
        }
        for (int t = 0; t < CLEN; ++t) {
            float dtv = dtp[(size_t)t * 512];
            float xiv = b2f(xip[(size_t)t * 512]);
            float zv  = b2f(zp[(size_t)t * 1024]);
            float dbx = dtv * xiv;
            float qv = __expf(dtv * a[0]);
            float q2 = qv * qv;
            f32x2 Q2 = (f32x2){q2, q2};
            f32x2 p  = (f32x2){qv, q2};
            f32x2 dbx2 = (f32x2){dbx, dbx};
            f32x2 yac = (f32x2){0.f, 0.f};
            const f32x2* bq = reinterpret_cast<const f32x2*>(Bsh[t]);
            const f32x2* cq = reinterpret_cast<const f32x2*>(Csh[t]);
            #pragma unroll
            for (int j = 0; j < 8; ++j) {
                f32x2 r = bq[j] * dbx2;
                h2[j] = PKFMA(p, h2[j], r);
                yac = PKFMA(h2[j], cq[j], yac);
                if (j < 7) p = p * Q2;
            }
            float yacc = yac[0] + yac[1];
            yp[(long)t * ystep] = f2b(fmaf(xiv, Dd, yacc) * siluf(zv));
        }
    } else {
        float h[16];
        {
            const float4* hp = reinterpret_cast<const float4*>(Hin + si);
            #pragma unroll
            for (int i = 0; i < 4; ++i) {
                float4 v = hp[i];
                h[4*i+0] = v.x; h[4*i+1] = v.y; h[4*i+2] = v.z; h[4*i+3] = v.w;
            }
        }
        for (int t = 0; t < CLEN; ++t) {
            float bn[16]; LD16(bn, Bsh[t]);
            float cn[16]; LD16(cn, Csh[t]);
            float dtv = dtp[(size_t)t * 512];
            float xiv = b2f(xip[(size_t)t * 512]);
            float zv  = b2f(zp[(size_t)t * 1024]);
            float dbx = dtv * xiv;
            float yacc = 0.f;
            #pragma unroll
            for (int n = 0; n < 16; ++n) {
                float dA = __expf(dtv * a[n]);
                h[n] = fmaf(dA, h[n], dbx * bn[n]);
                yacc = fmaf(h[n], cn[n], yacc);
            }
            yp[(long)t * ystep] = f2b(fmaf(xiv, Dd, yacc) * siluf(zv));
        }
    }
}

// ---------------------------------------------------------------------------
extern "C" void kernel_launch(void* const* d_in, const int* in_sizes, int n_in,
                              void* d_out, int out_size, void* d_ws, size_t ws_size,
                              hipStream_t stream)
{
    const float* x       = (const float*)d_in[0];
    const float* fW_in   = (const float*)d_in[1];
    const float* fconv_w = (const float*)d_in[2];
    const float* fconv_b = (const float*)d_in[3];
    const float* fW_x    = (const float*)d_in[4];
    const float* fW_dt   = (const float*)d_in[5];
    const float* fb_dt   = (const float*)d_in[6];
    const float* fA_log  = (const float*)d_in[7];
    const float* fD      = (const float*)d_in[8];
    const float* fW_out  = (const float*)d_in[9];
    const float* bW_in   = (const float*)d_in[10];
    const float* bconv_w = (const float*)d_in[11];
    const float* bconv_b = (const float*)d_in[12];
    const float* bW_x    = (const float*)d_in[13];
    const float* bW_dt   = (const float*)d_in[14];
    const float* bb_dt   = (const float*)d_in[15];
    const float* bA_log  = (const float*)d_in[16];
    const float* bD      = (const float*)d_in[17];
    const float* bW_out  = (const float*)d_in[18];
    const float* merge   = (const float*)d_in[19];
    float* out = (float*)d_out;

    char* ws = (char*)d_ws;
    ushort* xbh     = (ushort*)ws; ws += (size_t)ROWS * 256 * 2;
    ushort* WinT_f  = (ushort*)ws; ws += (size_t)1024 * 256 * 2;
    ushort* WinT_b  = (ushort*)ws; ws += (size_t)1024 * 256 * 2;
    ushort* WallOut = (ushort*)ws; ws += (size_t)256 * 1024 * 2;
    ushort* Wall_f  = (ushort*)ws; ws += (size_t)640 * 512 * 2;
    ushort* Wall_b  = (ushort*)ws; ws += (size_t)640 * 512 * 2;
    ushort* xz_f    = (ushort*)ws; ws += (size_t)ROWS * 1024 * 2;
    ushort* xz_b    = (ushort*)ws; ws += (size_t)ROWS * 1024 * 2;
    ushort* xi_f    = (ushort*)ws; ws += (size_t)ROWS * 512 * 2;
    ushort* xi_b    = (ushort*)ws; ws += (size_t)ROWS * 512 * 2;
    ushort* y_all   = (ushort*)ws; ws += (size_t)ROWS * 1024 * 2;
    float*  dt_f    = (float*)ws;  ws += (size_t)ROWS * 512 * 4;
    float*  dt_b    = (float*)ws;  ws += (size_t)ROWS * 512 * 4;
    float*  xd_f    = (float*)ws;  ws += (size_t)ROWS * 32 * 4;
    float*  xd_b    = (float*)ws;  ws += (size_t)ROWS * 32 * 4;
    float*  Acum    = (float*)ws;  ws += (size_t)4 * NCHUNK * 8192 * 4;
    float*  Hloc    = (float*)ws;  ws += (size_t)4 * NCHUNK * 8192 * 4;
    float*  Hin     = (float*)ws;  ws += (size_t)4 * NCHUNK * 8192 * 4;

    dim3 blk(256);

    // prep (single launch)
    prep_kernel<<<2624, blk, 0, stream>>>(x, fW_in, bW_in, fW_out, bW_out, merge,
                                          fW_x, fW_dt, bW_x, bW_dt,
                                          xbh, WinT_f, WinT_b, WallOut, Wall_f, Wall_b);

    // G1: xz = x @ W_in, both dirs (z picks dir; bw flips rows)  K=256
    mgemm<64, 128, 1><<<dim3(8, 128, 2), blk, 0, stream>>>(
        xbh, xbh, WinT_f, WinT_b, xz_f, xz_b, nullptr, nullptr, nullptr, nullptr,
        256, 1024, 0, 1, 1, 1);

    // conv + silu (both dirs)
    conv_kernel<<<4096, blk, 0, stream>>>(xz_f, xz_b, fconv_w, bconv_w,
                                          fconv_b, bconv_b, xi_f, xi_b);

    // dt+xd merged: [dt | xd | pad] = xi @ Wall^T (640 cols = 5x128 tiles)
    mgemm<64, 128, 2><<<dim3(5, 128, 2), blk, 0, stream>>>(
        xi_f, xi_b, Wall_f, Wall_b, dt_f, dt_b, fb_dt, bb_dt, xd_f, xd_b,
        512, 512, 0, 0, 1, 1);

    // chunked scan (packed-fp32 inner loops)
    scan_pass1<<<1024, blk, 0, stream>>>(xi_f, xi_b, dt_f, dt_b, xd_f, xd_b,
                                         fA_log, bA_log, Acum, Hloc);
    scan_pass2<<<128, blk, 0, stream>>>(Acum, Hloc, Hin);
    scan_pass3<<<1024, blk, 0, stream>>>(xi_f, xi_b, dt_f, dt_b, xd_f, xd_b,
                                         fA_log, bA_log, xz_f, xz_b, fD, bD,
                                         Hin, y_all);

    // G5: out = y_all @ WallOut^T  (single un-flipped GEMM, K=1024)
    mgemm<64, 64, 0><<<dim3(4, 128, 1), blk, 0, stream>>>(
        y_all, nullptr, WallOut, nullptr, out, nullptr, nullptr, nullptr,
        nullptr, nullptr, 1024, 256, 0, 0, 0, 1);
}